// Round 14
// baseline (260.233 us; speedup 1.0000x reference)
//
#include <hip/hip_runtime.h>

#define BB 4
#define HH 8
#define NSEQ 4096
#define DD 64
#define MM 266
#define CCH 128
#define NCH 32
#define NBH (BB*HH)
#define NROWS (NBH*NSEQ)

#define NORMALIZER 0.35355339059327373f
#define DIAGF 0.0625f
#define RATIO 0.0613140017f
#define KEPS 1e-4f
#define SBIAS 4.0f

typedef unsigned short ushort_t;
typedef unsigned int uint_t;

typedef __attribute__((ext_vector_type(8))) short bf16x8;
typedef __attribute__((ext_vector_type(4))) float f32x4;

__device__ __forceinline__ f32x4 mfma16(bf16x8 a, bf16x8 b, f32x4 c){
  return __builtin_amdgcn_mfma_f32_16x16x32_bf16(a, b, c, 0, 0, 0);
}

__device__ __forceinline__ ushort_t f2bf(float x){
  union { float f; uint_t u; } v; v.f = x;
  uint_t r = (v.u + 0x7FFFu + ((v.u >> 16) & 1u)) >> 16;
  return (ushort_t)r;
}
__device__ __forceinline__ float bf2f(ushort_t h){
  union { uint_t u; float f; } v; v.u = ((uint_t)h) << 16;
  return v.f;
}
__device__ __forceinline__ void unpack2(uint_t w, float& lo, float& hi){
  union { uint_t u; float f; } a, b;
  a.u = w << 16; b.u = w & 0xFFFF0000u;
  lo = a.f; hi = b.f;
}

// MFMA fragment load from a row-major LDS tile.
// lane l supplies element [spatial = s0 + (l&15)][k = koff + (l>>4)*8 + j], j=0..7
__device__ __forceinline__ bf16x8 frag_ld(const ushort_t* tile, int stride, int s0, int koff){
  const int l = threadIdx.x & 63;
  return *(const bf16x8*)(tile + (s0 + (l&15))*stride + koff + ((l>>4)<<3));
}

// ---------------- q projection: pass1 MFMA dash -> s' kept bf16-packed in regs;
// pass2 = exp+store only ----------------

__global__ __launch_bounds__(256) void k_dashq2(const float* __restrict__ x,
                                                const float* __restrict__ proj,
                                                ushort_t* __restrict__ qp){
  __shared__ __align__(16) ushort_t pjs[272*72];
  __shared__ __align__(16) ushort_t qs[128*72];
  __shared__ float diags[128];
  const int t = threadIdx.x;

  #pragma unroll
  for (int h=0; h<2; ++h){
    float2 pv[17];
    #pragma unroll
    for (int i=0;i<17;++i){
      int idx = t + (h*17+i)*256;
      int m = idx>>5, dp = (idx&31)*2;
      float2 p2 = {0.f,0.f};
      if (m < MM) p2 = *(const float2*)(proj + (size_t)m*DD + dp);
      pv[i] = p2;
    }
    #pragma unroll
    for (int i=0;i<17;++i){
      int idx = t + (h*17+i)*256;
      int m = idx>>5, dp = (idx&31)*2;
      *(uint_t*)(pjs + m*72 + dp) = (uint_t)f2bf(pv[i].x) | ((uint_t)f2bf(pv[i].y)<<16);
    }
  }
  {
    const int row = t>>1, half = t&1;
    const float2* xr = (const float2*)(x + ((size_t)blockIdx.x*128 + row)*DD + half*32);
    float ss = 0.f;
    #pragma unroll
    for (int i=0;i<16;++i){
      float2 a = xr[i];
      ss += a.x*a.x + a.y*a.y;
      uint_t w = (uint_t)f2bf(a.x*NORMALIZER) | ((uint_t)f2bf(a.y*NORMALIZER)<<16);
      *(uint_t*)(qs + row*72 + half*32 + i*2) = w;
    }
    ss += __shfl_xor(ss, 1);
    if (half==0) diags[row] = ss*DIAGF;
  }
  __syncthreads();

  const int l = t&63, wv = t>>6;
  const int wr0 = wv*32;
  float dv[2][4];
  #pragma unroll
  for (int rt=0;rt<2;++rt)
    #pragma unroll
    for (int r=0;r<4;++r) dv[rt][r] = diags[wr0 + rt*16 + ((l>>4)<<2) + r];

  float rmax[2][4];
  #pragma unroll
  for (int rt=0;rt<2;++rt){ rmax[rt][0]=-3e38f; rmax[rt][1]=-3e38f; rmax[rt][2]=-3e38f; rmax[rt][3]=-3e38f; }
  uint_t spu[17][2][2];
  #pragma unroll
  for (int mt=0; mt<17; ++mt){
    bf16x8 b0 = frag_ld(pjs, 72, mt*16, 0);
    bf16x8 b1 = frag_ld(pjs, 72, mt*16, 32);
    const bool valid = (mt*16 + (l&15)) < MM;
    #pragma unroll
    for (int rt=0;rt<2;++rt){
      bf16x8 a0 = frag_ld(qs, 72, wr0+rt*16, 0);
      bf16x8 a1 = frag_ld(qs, 72, wr0+rt*16, 32);
      f32x4 acc = {0.f,0.f,0.f,0.f};
      acc = mfma16(a0, b0, acc);
      acc = mfma16(a1, b1, acc);
      float sp0 = acc[0]-dv[rt][0]+SBIAS, sp1 = acc[1]-dv[rt][1]+SBIAS;
      float sp2 = acc[2]-dv[rt][2]+SBIAS, sp3 = acc[3]-dv[rt][3]+SBIAS;
      if (valid){
        rmax[rt][0] = fmaxf(rmax[rt][0], sp0); rmax[rt][1] = fmaxf(rmax[rt][1], sp1);
        rmax[rt][2] = fmaxf(rmax[rt][2], sp2); rmax[rt][3] = fmaxf(rmax[rt][3], sp3);
      }
      spu[mt][rt][0] = (uint_t)f2bf(sp0) | ((uint_t)f2bf(sp1)<<16);
      spu[mt][rt][1] = (uint_t)f2bf(sp2) | ((uint_t)f2bf(sp3)<<16);
    }
  }
  float sub[2][4];
  #pragma unroll
  for (int rt=0;rt<2;++rt){
    #pragma unroll
    for (int r=0;r<4;++r){
      float m = rmax[rt][r];
      m = fmaxf(m, __shfl_xor(m,1)); m = fmaxf(m, __shfl_xor(m,2));
      m = fmaxf(m, __shfl_xor(m,4)); m = fmaxf(m, __shfl_xor(m,8));
      // sub = max(s') + diag; the +diag is REQUIRED (R6 failure: eps does not cancel)
      sub[rt][r] = m + dv[rt][r];
    }
  }

  const size_t growb = (size_t)blockIdx.x*128;
  #pragma unroll
  for (int mt=0; mt<17; ++mt){
    const int m = mt*16 + (l&15);
    if (m < MM){
      #pragma unroll
      for (int rt=0;rt<2;++rt){
        float a0,a1,a2,a3;
        unpack2(spu[mt][rt][0], a0, a1);
        unpack2(spu[mt][rt][1], a2, a3);
        const size_t rb = growb + wr0 + rt*16 + ((l>>4)<<2);
        qp[(rb+0)*MM + m] = f2bf(RATIO*(__expf(a0 - sub[rt][0]) + KEPS));
        qp[(rb+1)*MM + m] = f2bf(RATIO*(__expf(a1 - sub[rt][1]) + KEPS));
        qp[(rb+2)*MM + m] = f2bf(RATIO*(__expf(a2 - sub[rt][2]) + KEPS));
        qp[(rb+3)*MM + m] = f2bf(RATIO*(__expf(a3 - sub[rt][3]) + KEPS));
      }
    }
  }
}

// ---------------- k dash: s' = dash - diag + SBIAS (bf16), rowsub = max(s')+diag ----------------

__global__ __launch_bounds__(256) void k_dashk(const float* __restrict__ x,
                                               const float* __restrict__ proj,
                                               ushort_t* __restrict__ sbuf,
                                               float* __restrict__ rowsub){
  __shared__ __align__(16) ushort_t pjs[272*72];
  __shared__ __align__(16) ushort_t qs[128*72];
  __shared__ float diags[128];
  const int t = threadIdx.x;

  #pragma unroll
  for (int h=0; h<2; ++h){
    float2 pv[17];
    #pragma unroll
    for (int i=0;i<17;++i){
      int idx = t + (h*17+i)*256;
      int m = idx>>5, dp = (idx&31)*2;
      float2 p2 = {0.f,0.f};
      if (m < MM) p2 = *(const float2*)(proj + (size_t)m*DD + dp);
      pv[i] = p2;
    }
    #pragma unroll
    for (int i=0;i<17;++i){
      int idx = t + (h*17+i)*256;
      int m = idx>>5, dp = (idx&31)*2;
      *(uint_t*)(pjs + m*72 + dp) = (uint_t)f2bf(pv[i].x) | ((uint_t)f2bf(pv[i].y)<<16);
    }
  }
  {
    const int row = t>>1, half = t&1;
    const float2* xr = (const float2*)(x + ((size_t)blockIdx.x*128 + row)*DD + half*32);
    float ss = 0.f;
    #pragma unroll
    for (int i=0;i<16;++i){
      float2 a = xr[i];
      ss += a.x*a.x + a.y*a.y;
      uint_t w = (uint_t)f2bf(a.x*NORMALIZER) | ((uint_t)f2bf(a.y*NORMALIZER)<<16);
      *(uint_t*)(qs + row*72 + half*32 + i*2) = w;
    }
    ss += __shfl_xor(ss, 1);
    if (half==0) diags[row] = ss*DIAGF;
  }
  __syncthreads();

  const int l = t&63, wv = t>>6;
  const int wr0 = wv*32;
  float dv[2][4];
  #pragma unroll
  for (int rt=0;rt<2;++rt)
    #pragma unroll
    for (int r=0;r<4;++r) dv[rt][r] = diags[wr0 + rt*16 + ((l>>4)<<2) + r];

  float rmax[2][4];
  #pragma unroll
  for (int rt=0;rt<2;++rt){ rmax[rt][0]=-3e38f; rmax[rt][1]=-3e38f; rmax[rt][2]=-3e38f; rmax[rt][3]=-3e38f; }

  const size_t growb = (size_t)blockIdx.x*128;
  for (int mt=0; mt<17; ++mt){
    bf16x8 b0 = frag_ld(pjs, 72, mt*16, 0);
    bf16x8 b1 = frag_ld(pjs, 72, mt*16, 32);
    const int m = mt*16 + (l&15);
    const bool valid = (m < MM);
    #pragma unroll
    for (int rt=0;rt<2;++rt){
      bf16x8 a0 = frag_ld(qs, 72, wr0+rt*16, 0);
      bf16x8 a1 = frag_ld(qs, 72, wr0+rt*16, 32);
      f32x4 acc = {0.f,0.f,0.f,0.f};
      acc = mfma16(a0, b0, acc);
      acc = mfma16(a1, b1, acc);
      #pragma unroll
      for (int r=0;r<4;++r){
        float sp = acc[r] - dv[rt][r] + SBIAS;
        if (valid){
          rmax[rt][r] = fmaxf(rmax[rt][r], sp);
          sbuf[(growb + wr0 + rt*16 + ((l>>4)<<2) + r)*MM + m] = f2bf(sp);
        }
      }
    }
  }
  #pragma unroll
  for (int rt=0;rt<2;++rt){
    #pragma unroll
    for (int r=0;r<4;++r){
      float m = rmax[rt][r];
      m = fmaxf(m, __shfl_xor(m,1)); m = fmaxf(m, __shfl_xor(m,2));
      m = fmaxf(m, __shfl_xor(m,4)); m = fmaxf(m, __shfl_xor(m,8));
      if ((l&15)==0)
        rowsub[growb + wr0 + rt*16 + ((l>>4)<<2) + r] = m + dv[rt][r];
    }
  }
}

// ---------------- global max (2-stage) ----------------

__global__ __launch_bounds__(256) void k_gmax1(const float* __restrict__ rowsub,
                                               float* __restrict__ part){
  __shared__ float s[4];
  int t = threadIdx.x;
  float m = rowsub[(size_t)blockIdx.x*256 + t];
  #pragma unroll
  for (int off=32; off>0; off>>=1) m = fmaxf(m, __shfl_xor(m, off));
  if ((t&63)==0) s[t>>6] = m;
  __syncthreads();
  if (t==0) part[blockIdx.x] = fmaxf(fmaxf(s[0],s[1]), fmaxf(s[2],s[3]));
}

__global__ __launch_bounds__(256) void k_gmax2(const float* __restrict__ part,
                                               float* __restrict__ gmax){
  __shared__ float s[4];
  int t = threadIdx.x;
  float m = fmaxf(part[t], part[t+256]);
  #pragma unroll
  for (int off=32; off>0; off>>=1) m = fmaxf(m, __shfl_xor(m, off));
  if ((t&63)==0) s[t>>6] = m;
  __syncthreads();
  if (t==0) gmax[0] = fmaxf(fmaxf(s[0],s[1]), fmaxf(s[2],s[3]));
}

// ---------------- chunk sums via MFMA; b32 colsum, b128 vT staging (stride 140) ----------------

__global__ __launch_bounds__(256) void k_chunksum6(const ushort_t* __restrict__ kd,
                                                   const float* __restrict__ v,
                                                   const float* __restrict__ gmaxp,
                                                   ushort_t* __restrict__ ctx,
                                                   float* __restrict__ z){
  __shared__ __align__(16) ushort_t kpT[272*34];  // [m][row-subtile 32], 18,496 B
  __shared__ __align__(16) ushort_t vT[64*140];   // [e][row 128], stride 140 (70 dw == 6 mod 32)
  const int blk = blockIdx.x, bh = blk>>5, ch = blk&31;
  const int t = threadIdx.x, l = t&63, wv = t>>6;
  const int row0 = ch*CCH;
  const ushort_t* kg = kd + (size_t)(bh*NSEQ + row0)*MM;
  const float*    vg = v  + (size_t)(bh*NSEQ + row0)*DD;
  const float g = gmaxp[0];

  // stage V transposed: 32 coalesced loads + 4 ds_write_b128 per thread
  {
    const int e = t&63, gq = t>>6;   // gq in 0..3 -> rows 32gq..32gq+31
    #pragma unroll
    for (int s=0;s<4;++s){
      union { ushort_t us[8]; bf16x8 v8; } u;
      #pragma unroll
      for (int j=0;j<8;++j)
        u.us[j] = f2bf(vg[(size_t)(32*gq + 8*s + j)*DD + e]);
      *(bf16x8*)(vT + e*140 + 32*gq + 8*s) = u.v8;
    }
  }
  for (int idx=t; idx<6*34; idx+=256) kpT[266*34 + idx] = 0;

  const int rloc  = t>>3;
  const int mlane = t&7;
  const bool hastail = (mlane < 5);
  uint_t rw[17];

#define CLOAD(KS) do{ \
    const ushort_t* src_ = kg + (size_t)((KS)*32 + rloc)*MM; \
    _Pragma("unroll") \
    for (int j=0;j<16;++j) rw[j] = *(const uint_t*)(src_ + 2*(j*8 + mlane)); \
    rw[16] = hastail ? *(const uint_t*)(src_ + 2*(128 + mlane)) : 0u; \
  }while(0)

#define CSTORE() do{ \
    _Pragma("unroll") \
    for (int j=0;j<16;++j){ \
      float a_, b_; unpack2(rw[j], a_, b_); \
      const int m_ = 2*(j*8 + mlane); \
      kpT[(m_  )*34 + rloc] = f2bf(RATIO*(__expf(a_ - g) + KEPS)); \
      kpT[(m_+1)*34 + rloc] = f2bf(RATIO*(__expf(b_ - g) + KEPS)); \
    } \
    if (hastail){ \
      float a_, b_; unpack2(rw[16], a_, b_); \
      const int m_ = 2*(128 + mlane); \
      kpT[(m_  )*34 + rloc] = f2bf(RATIO*(__expf(a_ - g) + KEPS)); \
      kpT[(m_+1)*34 + rloc] = f2bf(RATIO*(__expf(b_ - g) + KEPS)); \
    } \
  }while(0)

  f32x4 acc[17];
  #pragma unroll
  for (int i=0;i<17;++i) acc[i] = (f32x4){0.f,0.f,0.f,0.f};
  float zacc = 0.f, zacc2 = 0.f;
  const bool hasz2 = (256 + t) < MM;

  CLOAD(0);
  for (int ks=0; ks<4; ++ks){
    __syncthreads();
    CSTORE();
    __syncthreads();
    if (ks < 3) CLOAD(ks+1);

    {
      float s1 = 0.f;
      #pragma unroll
      for (int j=0;j<16;++j){
        float a_, b_; unpack2(*(const uint_t*)(kpT + t*34 + 2*j), a_, b_);
        s1 += a_; s1 += b_;
      }
      zacc += s1;
      if (t < 16){
        float s2 = 0.f;
        #pragma unroll
        for (int j=0;j<16;++j){
          float a_, b_; unpack2(*(const uint_t*)(kpT + (256+t)*34 + 2*j), a_, b_);
          s2 += a_; s2 += b_;
        }
        zacc2 += s2;
      }
    }
    bf16x8 bv = frag_ld(vT, 140, wv*16, ks*32);
    #pragma unroll
    for (int mt=0; mt<17; ++mt){
      bf16x8 a = frag_ld(kpT, 34, mt*16, 0);
      acc[mt] = mfma16(a, bv, acc[mt]);
    }
  }

  ushort_t* cg = ctx + (size_t)blk*MM*DD;
  const int e = wv*16 + (l&15);
  #pragma unroll
  for (int mt=0; mt<17; ++mt){
    #pragma unroll
    for (int r=0;r<4;++r){
      int m = mt*16 + ((l>>4)<<2) + r;
      if (m < MM) cg[(size_t)m*DD + e] = f2bf(acc[mt][r]);
    }
  }
  float* zgo = z + (size_t)blk*MM;
  zgo[t] = zacc;
  if (hasz2) zgo[256+t] = zacc2;
#undef CLOAD
#undef CSTORE
}

// ---------------- exclusive prefix over chunks (batched; ctx bf16, f32 accumulate) ----------------

__global__ __launch_bounds__(256) void k_prefix_ctx2(ushort_t* __restrict__ ctx){
  int blk = blockIdx.x; int bh = blk/67, mg = blk%67;
  int t = threadIdx.x; int mo = t>>6, e = t&63;
  int m = mg*4 + mo;
  if (m >= MM) return;
  size_t base = (size_t)bh*NCH*MM*DD + (size_t)m*DD + e;
  float vals[32];
  #pragma unroll
  for (int c=0;c<NCH;++c) vals[c] = bf2f(ctx[base + (size_t)c*MM*DD]);
  float run = 0.f;
  #pragma unroll
  for (int c=0;c<NCH;++c){
    float cur = vals[c];
    ctx[base + (size_t)c*MM*DD] = f2bf(run);
    run += cur;
  }
}

__global__ __launch_bounds__(256) void k_prefix_z2(float* __restrict__ z){
  int bh = blockIdx.x, t = threadIdx.x;
  size_t base = (size_t)bh*NCH*MM;
  {
    float va[32];
    #pragma unroll
    for (int c=0;c<NCH;++c) va[c] = z[base + (size_t)c*MM + t];
    float run = 0.f;
    #pragma unroll
    for (int c=0;c<NCH;++c){ float cur = va[c]; z[base + (size_t)c*MM + t] = run; run += cur; }
  }
  if (256 + t < MM){
    float vb[32];
    #pragma unroll
    for (int c=0;c<NCH;++c) vb[c] = z[base + (size_t)c*MM + 256 + t];
    float run = 0.f;
    #pragma unroll
    for (int c=0;c<NCH;++c){ float cur = vb[c]; z[base + (size_t)c*MM + 256 + t] = run; run += cur; }
  }
}

// ---------------- per-chunk output: conflict-tuned strides (Ps/vT 140, ctxT 76) ----------------
// LDS: qs/kss [0,36864) -> Ps [0,35840) + vT [35840,53760); ctxT [36864,49024) dies at
// m-loop end (vT written after barrier). 53,760 B -> 3 blocks/CU. No launch cap (R7/R10).

__global__ __launch_bounds__(512) void k_output11(const ushort_t* __restrict__ qp,
                                                  const ushort_t* __restrict__ kd,
                                                  const float* __restrict__ v,
                                                  const ushort_t* __restrict__ ctx,
                                                  const float* __restrict__ z,
                                                  const float* __restrict__ gmaxp,
                                                  float* __restrict__ out){
  __shared__ __align__(16) char lds[53760];
  ushort_t* qs   = (ushort_t*)lds;            // [128][72]  18,432 B
  ushort_t* kss  = (ushort_t*)(lds + 18432);  // [128][72]  18,432 B
  ushort_t* Ps   = (ushort_t*)lds;            // [128][140] 35,840 B (aliases qs+kss)
  ushort_t* ctxT = (ushort_t*)(lds + 36864);  // [80][76]   12,160 B (e-major; e=64 is z; dead post m-loop)
  ushort_t* vT   = (ushort_t*)(lds + 35840);  // [64][140]  17,920 B (after Ps; overwrites ctxT region)

  const int blk = blockIdx.x, bh = blk>>5, ch = blk&31;
  const int t = threadIdx.x, l = t&63, wv = t>>6;   // wv in 0..7
  const int row0 = ch*CCH;
  const int wr0 = wv*16;
  const float g = gmaxp[0];

  const ushort_t* qg = qp + (size_t)(bh*NSEQ + row0)*MM;
  const ushort_t* kg = kd + (size_t)(bh*NSEQ + row0)*MM;
  const float*    vg = v  + (size_t)(bh*NSEQ + row0)*DD;
  const ushort_t* ctxg = ctx + (size_t)blk*MM*DD;
  const float*    zg = z  + (size_t)blk*MM;

  // register prefetch state
  const int mcol  = (t&31)<<1;   // q/k: m-offset within 64-tile (uint granularity)
  const int qrow0 = t>>5;        // q/k: rows qrow0 + 16i (qrow0 in 0..15)
  const int ce    = t&63;        // ctx/v: e
  uint_t rq[8], rk[8];
  union { ushort_t us[8]; bf16x8 v8; } rc;   // ctx m-block: m = 8*wv + 0..7
  float rz;

#define LOADREGS(MT) do{ \
    const int m0_ = (MT)*64; \
    const bool vq_ = (m0_ + mcol) < MM; \
    _Pragma("unroll") \
    for (int i=0;i<8;++i){ \
      int row_ = qrow0 + 16*i; \
      rq[i] = vq_ ? *(const uint_t*)(qg + (size_t)row_*MM + m0_ + mcol) : 0u; \
      rk[i] = vq_ ? *(const uint_t*)(kg + (size_t)row_*MM + m0_ + mcol) : 0u; \
    } \
    _Pragma("unroll") \
    for (int j=0;j<8;++j){ \
      int mm_ = m0_ + 8*wv + j; \
      rc.us[j] = (mm_ < MM) ? ctxg[(size_t)mm_*DD + ce] : (ushort_t)0; \
    } \
    rz = (m0_ + (t&63) < MM) ? zg[m0_ + (t&63)] : 0.f; \
  }while(0)

#define WRITELDS(MT) do{ \
    const int m0_ = (MT)*64; \
    const bool vq_ = (m0_ + mcol) < MM; \
    _Pragma("unroll") \
    for (int i=0;i<8;++i){ \
      int row_ = qrow0 + 16*i; \
      *(uint_t*)(qs + row_*72 + mcol) = rq[i]; \
      uint_t ko_ = 0u; \
      if (vq_){ \
        float a_, b_; unpack2(rk[i], a_, b_); \
        a_ = RATIO*(__expf(a_ - g) + KEPS); \
        b_ = RATIO*(__expf(b_ - g) + KEPS); \
        ko_ = (uint_t)f2bf(a_) | ((uint_t)f2bf(b_)<<16); \
      } \
      *(uint_t*)(kss + row_*72 + mcol) = ko_; \
    } \
    *(bf16x8*)(ctxT + ce*76 + 8*wv) = rc.v8; \
    if (t < 64) ctxT[64*76 + t] = f2bf(rz); \
  }while(0)

  // zero the ctxT pad e-rows 65..79 once (never rewritten during m-loop)
  for (int idx=t; idx<15*76; idx+=512) ctxT[65*76 + idx] = 0;

  f32x4 acc[8];
  f32x4 oacc[5];
  #pragma unroll
  for (int ct=0;ct<8;++ct) acc[ct] = (f32x4){0.f,0.f,0.f,0.f};
  #pragma unroll
  for (int et=0;et<5;++et) oacc[et] = (f32x4){0.f,0.f,0.f,0.f};

  LOADREGS(0);
  for (int mt=0; mt<5; ++mt){
    __syncthreads();
    WRITELDS(mt);
    __syncthreads();
    if (mt < 4) LOADREGS(mt+1);

    bf16x8 aq[2];
    aq[0] = frag_ld(qs, 72, wr0, 0);
    aq[1] = frag_ld(qs, 72, wr0, 32);
    #pragma unroll
    for (int ct=0;ct<8;++ct){
      bf16x8 b0 = frag_ld(kss, 72, ct*16, 0);
      bf16x8 b1 = frag_ld(kss, 72, ct*16, 32);
      acc[ct] = mfma16(aq[0], b0, acc[ct]);
      acc[ct] = mfma16(aq[1], b1, acc[ct]);
    }
    #pragma unroll
    for (int et=0;et<5;++et){
      bf16x8 b0 = frag_ld(ctxT, 76, et*16, 0);
      bf16x8 b1 = frag_ld(ctxT, 76, et*16, 32);
      oacc[et] = mfma16(aq[0], b0, oacc[et]);
      oacc[et] = mfma16(aq[1], b1, oacc[et]);
    }
  }
  __syncthreads();  // all MFMA readers done before Ps/vT overwrite qs/kss/ctxT

  // issue V loads early (rows 8wv..+7 and 64+8wv..+7 at e=ce)
  float rv[16];
  {
    #pragma unroll
    for (int j=0;j<8;++j)  rv[j]   = vg[(size_t)(8*wv + j)*DD + ce];
    #pragma unroll
    for (int j=0;j<8;++j)  rv[8+j] = vg[(size_t)(64 + 8*wv + j)*DD + ce];
  }

  // ---- mask + row-sum + write P (bf16) to LDS (stride 140 -> 2-way scatter) ----
  float ds[4] = {0.f,0.f,0.f,0.f};
  #pragma unroll
  for (int ct=0;ct<8;++ct){
    #pragma unroll
    for (int r=0;r<4;++r){
      int i = wr0 + ((l>>4)<<2) + r;
      int j = ct*16 + (l&15);
      float m = (j <= i) ? acc[ct][r] : 0.f;
      acc[ct][r] = m;
      ds[r] += m;
    }
  }
  #pragma unroll
  for (int ct=0;ct<8;++ct){
    #pragma unroll
    for (int r=0;r<4;++r){
      int i = wr0 + ((l>>4)<<2) + r;
      Ps[i*140 + ct*16 + (l&15)] = f2bf(acc[ct][r]);
    }
  }
  // full D per lane: masked-S rowsum + z-dot from MFMA e-column 64
  float dtot[4];
  #pragma unroll
  for (int r=0;r<4;++r){
    float d = ds[r];
    d += __shfl_xor(d,1); d += __shfl_xor(d,2); d += __shfl_xor(d,4); d += __shfl_xor(d,8);
    dtot[r] = d + __shfl(oacc[4][r], l & 48);
  }
  // write V transposed via 2 ds_write_b128 per thread
  {
    union { ushort_t us[8]; bf16x8 v8; } u0, u1;
    #pragma unroll
    for (int j=0;j<8;++j){ u0.us[j] = f2bf(rv[j]); u1.us[j] = f2bf(rv[8+j]); }
    *(bf16x8*)(vT + ce*140 + 8*wv) = u0.v8;
    *(bf16x8*)(vT + ce*140 + 64 + 8*wv) = u1.v8;
  }
  __syncthreads();

  // ---- PV: oacc += P V ----
  #pragma unroll
  for (int kt=0;kt<4;++kt){
    bf16x8 ap = frag_ld(Ps, 140, wr0, kt*32);
    #pragma unroll
    for (int et=0;et<4;++et){
      bf16x8 bv = frag_ld(vT, 140, et*16, kt*32);
      oacc[et] = mfma16(ap, bv, oacc[et]);
    }
  }

  // ---- epilogue ----
  float* og = out + (size_t)(bh*NSEQ + row0)*DD;
  #pragma unroll
  for (int r=0;r<4;++r){
    int i = wr0 + ((l>>4)<<2) + r;
    float dinv = 1.0f / dtot[r];
    #pragma unroll
    for (int et=0;et<4;++et)
      og[(size_t)i*DD + et*16 + (l&15)] = oacc[et][r] * dinv;
  }
#undef LOADREGS
#undef WRITELDS
}

// ---------------- launch ----------------

extern "C" void kernel_launch(void* const* d_in, const int* in_sizes, int n_in,
                              void* d_out, int out_size, void* d_ws, size_t ws_size,
                              hipStream_t stream) {
  const float* q    = (const float*)d_in[0];
  const float* k    = (const float*)d_in[1];
  const float* v    = (const float*)d_in[2];
  const float* proj = (const float*)d_in[3];
  float* out = (float*)d_out;
  char* ws = (char*)d_ws;

  const size_t QP_OFF   = 0;             // bf16 [rows][266]  final qp
  const size_t KD_OFF   = 69730304ull;   // bf16 [rows][266]  s'_k (pre-exp)
  const size_t CTX_OFF  = 139460608ull;  // bf16 [1024][266][64] = 34,865,152
  const size_t Z_OFF    = 174325760ull;  // f32  [1024][266] = 1,089,536
  const size_t RSUB_OFF = 175415296ull;  // f32  [rows] = 524,288
  const size_t PART_OFF = 175939584ull;  // f32  [512]
  const size_t GMAX_OFF = 175941632ull;  // f32  [1]
  if (ws_size < 175942000ull) return;

  ushort_t* qp   = (ushort_t*)(ws + QP_OFF);
  ushort_t* kd   = (ushort_t*)(ws + KD_OFF);
  ushort_t* ctx  = (ushort_t*)(ws + CTX_OFF);
  float* z       = (float*)(ws + Z_OFF);
  float* rowsub  = (float*)(ws + RSUB_OFF);
  float* part    = (float*)(ws + PART_OFF);
  float* gmax    = (float*)(ws + GMAX_OFF);

  k_dashq2 <<<NROWS/128, 256, 0, stream>>>(q, proj, qp);
  k_dashk  <<<NROWS/128, 256, 0, stream>>>(k, proj, kd, rowsub);
  k_gmax1  <<<512, 256, 0, stream>>>(rowsub, part);
  k_gmax2  <<<1, 256, 0, stream>>>(part, gmax);
  k_chunksum6 <<<NBH*NCH, 256, 0, stream>>>(kd, v, gmax, ctx, z);
  k_prefix_ctx2<<<NBH*67, 256, 0, stream>>>(ctx);
  k_prefix_z2 <<<NBH, 256, 0, stream>>>(z);
  k_output11  <<<NBH*NCH, 512, 0, stream>>>(qp, kd, v, ctx, z, gmax, out);
}

// Round 15
// 203.754 us; speedup vs baseline: 1.2772x; 1.2772x over previous
//
#include <hip/hip_runtime.h>

#define BB 4
#define HH 8
#define NSEQ 4096
#define DD 64
#define MM 266
#define CCH 128
#define NCH 32
#define NBH (BB*HH)
#define NROWS (NBH*NSEQ)

#define NORMALIZER 0.35355339059327373f
#define DIAGF 0.0625f
#define RATIO 0.0613140017f
#define KEPS 1e-4f
#define SBIAS 4.0f

typedef unsigned short ushort_t;
typedef unsigned int uint_t;

typedef __attribute__((ext_vector_type(8))) short bf16x8;
typedef __attribute__((ext_vector_type(4))) float f32x4;

__device__ __forceinline__ f32x4 mfma16(bf16x8 a, bf16x8 b, f32x4 c){
  return __builtin_amdgcn_mfma_f32_16x16x32_bf16(a, b, c, 0, 0, 0);
}

__device__ __forceinline__ ushort_t f2bf(float x){
  union { float f; uint_t u; } v; v.f = x;
  uint_t r = (v.u + 0x7FFFu + ((v.u >> 16) & 1u)) >> 16;
  return (ushort_t)r;
}
__device__ __forceinline__ float bf2f(ushort_t h){
  union { uint_t u; float f; } v; v.u = ((uint_t)h) << 16;
  return v.f;
}
__device__ __forceinline__ void unpack2(uint_t w, float& lo, float& hi){
  union { uint_t u; float f; } a, b;
  a.u = w << 16; b.u = w & 0xFFFF0000u;
  lo = a.f; hi = b.f;
}

// MFMA fragment load from a row-major LDS tile.
// lane l supplies element [spatial = s0 + (l&15)][k = koff + (l>>4)*8 + j], j=0..7
// NOTE (R14 lesson): stride (in ushorts) MUST be a multiple of 8 so bf16x8 LDS
// accesses stay 16B-aligned; 140/76 (== 8 mod 16 bytes for odd rows) split every
// ds_*_b128 and cost 2x. 72 and 136 are the verified-aligned choices.
__device__ __forceinline__ bf16x8 frag_ld(const ushort_t* tile, int stride, int s0, int koff){
  const int l = threadIdx.x & 63;
  return *(const bf16x8*)(tile + (s0 + (l&15))*stride + koff + ((l>>4)<<3));
}

// ---------------- q projection: pass1 MFMA dash -> s' kept bf16-packed in regs;
// pass2 = exp+store only (no second MFMA sweep) ----------------

__global__ __launch_bounds__(256) void k_dashq2(const float* __restrict__ x,
                                                const float* __restrict__ proj,
                                                ushort_t* __restrict__ qp){
  __shared__ __align__(16) ushort_t pjs[272*72];
  __shared__ __align__(16) ushort_t qs[128*72];
  __shared__ float diags[128];
  const int t = threadIdx.x;

  #pragma unroll
  for (int h=0; h<2; ++h){
    float2 pv[17];
    #pragma unroll
    for (int i=0;i<17;++i){
      int idx = t + (h*17+i)*256;
      int m = idx>>5, dp = (idx&31)*2;
      float2 p2 = {0.f,0.f};
      if (m < MM) p2 = *(const float2*)(proj + (size_t)m*DD + dp);
      pv[i] = p2;
    }
    #pragma unroll
    for (int i=0;i<17;++i){
      int idx = t + (h*17+i)*256;
      int m = idx>>5, dp = (idx&31)*2;
      *(uint_t*)(pjs + m*72 + dp) = (uint_t)f2bf(pv[i].x) | ((uint_t)f2bf(pv[i].y)<<16);
    }
  }
  {
    const int row = t>>1, half = t&1;
    const float2* xr = (const float2*)(x + ((size_t)blockIdx.x*128 + row)*DD + half*32);
    float ss = 0.f;
    #pragma unroll
    for (int i=0;i<16;++i){
      float2 a = xr[i];
      ss += a.x*a.x + a.y*a.y;
      uint_t w = (uint_t)f2bf(a.x*NORMALIZER) | ((uint_t)f2bf(a.y*NORMALIZER)<<16);
      *(uint_t*)(qs + row*72 + half*32 + i*2) = w;
    }
    ss += __shfl_xor(ss, 1);
    if (half==0) diags[row] = ss*DIAGF;
  }
  __syncthreads();

  const int l = t&63, wv = t>>6;
  const int wr0 = wv*32;
  float dv[2][4];
  #pragma unroll
  for (int rt=0;rt<2;++rt)
    #pragma unroll
    for (int r=0;r<4;++r) dv[rt][r] = diags[wr0 + rt*16 + ((l>>4)<<2) + r];

  float rmax[2][4];
  #pragma unroll
  for (int rt=0;rt<2;++rt){ rmax[rt][0]=-3e38f; rmax[rt][1]=-3e38f; rmax[rt][2]=-3e38f; rmax[rt][3]=-3e38f; }
  uint_t spu[17][2][2];
  #pragma unroll
  for (int mt=0; mt<17; ++mt){
    bf16x8 b0 = frag_ld(pjs, 72, mt*16, 0);
    bf16x8 b1 = frag_ld(pjs, 72, mt*16, 32);
    const bool valid = (mt*16 + (l&15)) < MM;
    #pragma unroll
    for (int rt=0;rt<2;++rt){
      bf16x8 a0 = frag_ld(qs, 72, wr0+rt*16, 0);
      bf16x8 a1 = frag_ld(qs, 72, wr0+rt*16, 32);
      f32x4 acc = {0.f,0.f,0.f,0.f};
      acc = mfma16(a0, b0, acc);
      acc = mfma16(a1, b1, acc);
      float sp0 = acc[0]-dv[rt][0]+SBIAS, sp1 = acc[1]-dv[rt][1]+SBIAS;
      float sp2 = acc[2]-dv[rt][2]+SBIAS, sp3 = acc[3]-dv[rt][3]+SBIAS;
      if (valid){
        rmax[rt][0] = fmaxf(rmax[rt][0], sp0); rmax[rt][1] = fmaxf(rmax[rt][1], sp1);
        rmax[rt][2] = fmaxf(rmax[rt][2], sp2); rmax[rt][3] = fmaxf(rmax[rt][3], sp3);
      }
      spu[mt][rt][0] = (uint_t)f2bf(sp0) | ((uint_t)f2bf(sp1)<<16);
      spu[mt][rt][1] = (uint_t)f2bf(sp2) | ((uint_t)f2bf(sp3)<<16);
    }
  }
  float sub[2][4];
  #pragma unroll
  for (int rt=0;rt<2;++rt){
    #pragma unroll
    for (int r=0;r<4;++r){
      float m = rmax[rt][r];
      m = fmaxf(m, __shfl_xor(m,1)); m = fmaxf(m, __shfl_xor(m,2));
      m = fmaxf(m, __shfl_xor(m,4)); m = fmaxf(m, __shfl_xor(m,8));
      // sub = max(s') + diag; the +diag is REQUIRED (R6 failure: eps does not cancel)
      sub[rt][r] = m + dv[rt][r];
    }
  }

  const size_t growb = (size_t)blockIdx.x*128;
  #pragma unroll
  for (int mt=0; mt<17; ++mt){
    const int m = mt*16 + (l&15);
    if (m < MM){
      #pragma unroll
      for (int rt=0;rt<2;++rt){
        float a0,a1,a2,a3;
        unpack2(spu[mt][rt][0], a0, a1);
        unpack2(spu[mt][rt][1], a2, a3);
        const size_t rb = growb + wr0 + rt*16 + ((l>>4)<<2);
        qp[(rb+0)*MM + m] = f2bf(RATIO*(__expf(a0 - sub[rt][0]) + KEPS));
        qp[(rb+1)*MM + m] = f2bf(RATIO*(__expf(a1 - sub[rt][1]) + KEPS));
        qp[(rb+2)*MM + m] = f2bf(RATIO*(__expf(a2 - sub[rt][2]) + KEPS));
        qp[(rb+3)*MM + m] = f2bf(RATIO*(__expf(a3 - sub[rt][3]) + KEPS));
      }
    }
  }
}

// ---------------- k dash: s' = dash - diag + SBIAS (bf16), rowsub = max(s')+diag ----------------

__global__ __launch_bounds__(256) void k_dashk(const float* __restrict__ x,
                                               const float* __restrict__ proj,
                                               ushort_t* __restrict__ sbuf,
                                               float* __restrict__ rowsub){
  __shared__ __align__(16) ushort_t pjs[272*72];
  __shared__ __align__(16) ushort_t qs[128*72];
  __shared__ float diags[128];
  const int t = threadIdx.x;

  #pragma unroll
  for (int h=0; h<2; ++h){
    float2 pv[17];
    #pragma unroll
    for (int i=0;i<17;++i){
      int idx = t + (h*17+i)*256;
      int m = idx>>5, dp = (idx&31)*2;
      float2 p2 = {0.f,0.f};
      if (m < MM) p2 = *(const float2*)(proj + (size_t)m*DD + dp);
      pv[i] = p2;
    }
    #pragma unroll
    for (int i=0;i<17;++i){
      int idx = t + (h*17+i)*256;
      int m = idx>>5, dp = (idx&31)*2;
      *(uint_t*)(pjs + m*72 + dp) = (uint_t)f2bf(pv[i].x) | ((uint_t)f2bf(pv[i].y)<<16);
    }
  }
  {
    const int row = t>>1, half = t&1;
    const float2* xr = (const float2*)(x + ((size_t)blockIdx.x*128 + row)*DD + half*32);
    float ss = 0.f;
    #pragma unroll
    for (int i=0;i<16;++i){
      float2 a = xr[i];
      ss += a.x*a.x + a.y*a.y;
      uint_t w = (uint_t)f2bf(a.x*NORMALIZER) | ((uint_t)f2bf(a.y*NORMALIZER)<<16);
      *(uint_t*)(qs + row*72 + half*32 + i*2) = w;
    }
    ss += __shfl_xor(ss, 1);
    if (half==0) diags[row] = ss*DIAGF;
  }
  __syncthreads();

  const int l = t&63, wv = t>>6;
  const int wr0 = wv*32;
  float dv[2][4];
  #pragma unroll
  for (int rt=0;rt<2;++rt)
    #pragma unroll
    for (int r=0;r<4;++r) dv[rt][r] = diags[wr0 + rt*16 + ((l>>4)<<2) + r];

  float rmax[2][4];
  #pragma unroll
  for (int rt=0;rt<2;++rt){ rmax[rt][0]=-3e38f; rmax[rt][1]=-3e38f; rmax[rt][2]=-3e38f; rmax[rt][3]=-3e38f; }

  const size_t growb = (size_t)blockIdx.x*128;
  for (int mt=0; mt<17; ++mt){
    bf16x8 b0 = frag_ld(pjs, 72, mt*16, 0);
    bf16x8 b1 = frag_ld(pjs, 72, mt*16, 32);
    const int m = mt*16 + (l&15);
    const bool valid = (m < MM);
    #pragma unroll
    for (int rt=0;rt<2;++rt){
      bf16x8 a0 = frag_ld(qs, 72, wr0+rt*16, 0);
      bf16x8 a1 = frag_ld(qs, 72, wr0+rt*16, 32);
      f32x4 acc = {0.f,0.f,0.f,0.f};
      acc = mfma16(a0, b0, acc);
      acc = mfma16(a1, b1, acc);
      #pragma unroll
      for (int r=0;r<4;++r){
        float sp = acc[r] - dv[rt][r] + SBIAS;
        if (valid){
          rmax[rt][r] = fmaxf(rmax[rt][r], sp);
          sbuf[(growb + wr0 + rt*16 + ((l>>4)<<2) + r)*MM + m] = f2bf(sp);
        }
      }
    }
  }
  #pragma unroll
  for (int rt=0;rt<2;++rt){
    #pragma unroll
    for (int r=0;r<4;++r){
      float m = rmax[rt][r];
      m = fmaxf(m, __shfl_xor(m,1)); m = fmaxf(m, __shfl_xor(m,2));
      m = fmaxf(m, __shfl_xor(m,4)); m = fmaxf(m, __shfl_xor(m,8));
      if ((l&15)==0)
        rowsub[growb + wr0 + rt*16 + ((l>>4)<<2) + r] = m + dv[rt][r];
    }
  }
}

// ---------------- global max (2-stage) ----------------

__global__ __launch_bounds__(256) void k_gmax1(const float* __restrict__ rowsub,
                                               float* __restrict__ part){
  __shared__ float s[4];
  int t = threadIdx.x;
  float m = rowsub[(size_t)blockIdx.x*256 + t];
  #pragma unroll
  for (int off=32; off>0; off>>=1) m = fmaxf(m, __shfl_xor(m, off));
  if ((t&63)==0) s[t>>6] = m;
  __syncthreads();
  if (t==0) part[blockIdx.x] = fmaxf(fmaxf(s[0],s[1]), fmaxf(s[2],s[3]));
}

__global__ __launch_bounds__(256) void k_gmax2(const float* __restrict__ part,
                                               float* __restrict__ gmax){
  __shared__ float s[4];
  int t = threadIdx.x;
  float m = fmaxf(part[t], part[t+256]);
  #pragma unroll
  for (int off=32; off>0; off>>=1) m = fmaxf(m, __shfl_xor(m, off));
  if ((t&63)==0) s[t>>6] = m;
  __syncthreads();
  if (t==0) gmax[0] = fmaxf(fmaxf(s[0],s[1]), fmaxf(s[2],s[3]));
}

// ---------------- chunk sums via MFMA; b32 colsum + pair-packed vT staging ----------------

__global__ __launch_bounds__(256) void k_chunksum5(const ushort_t* __restrict__ kd,
                                                   const float* __restrict__ v,
                                                   const float* __restrict__ gmaxp,
                                                   ushort_t* __restrict__ ctx,
                                                   float* __restrict__ z){
  __shared__ __align__(16) ushort_t kpT[272*34];  // [m][row-subtile 32]
  __shared__ __align__(16) ushort_t vT[64*136];   // [e][row 128]
  const int blk = blockIdx.x, bh = blk>>5, ch = blk&31;
  const int t = threadIdx.x, l = t&63, wv = t>>6;
  const int row0 = ch*CCH;
  const ushort_t* kg = kd + (size_t)(bh*NSEQ + row0)*MM;
  const float*    vg = v  + (size_t)(bh*NSEQ + row0)*DD;
  const float g = gmaxp[0];

  // stage V transposed: row-pairs packed as uints (16 stores instead of 32)
  {
    const int e = t&63, rp = t>>6;   // rp in 0..3; pair index rp+4i, i=0..15
    float rv[32];
    #pragma unroll
    for (int i=0;i<16;++i){
      rv[2*i]   = vg[(size_t)(2*(rp+4*i)  )*DD + e];
      rv[2*i+1] = vg[(size_t)(2*(rp+4*i)+1)*DD + e];
    }
    #pragma unroll
    for (int i=0;i<16;++i)
      *(uint_t*)(vT + e*136 + 2*(rp+4*i)) =
        (uint_t)f2bf(rv[2*i]) | ((uint_t)f2bf(rv[2*i+1])<<16);
  }
  // zero-fill pad m-rows 266..271 once (loop never writes m>=266)
  for (int idx=t; idx<6*34; idx+=256) kpT[266*34 + idx] = 0;

  const int rloc  = t>>3;   // row within 32-row ks-tile (0..31)
  const int mlane = t&7;    // 8 load-lanes per row
  const bool hastail = (mlane < 5);
  uint_t rw[17];

#define CLOAD(KS) do{ \
    const ushort_t* src_ = kg + (size_t)((KS)*32 + rloc)*MM; \
    _Pragma("unroll") \
    for (int j=0;j<16;++j) rw[j] = *(const uint_t*)(src_ + 2*(j*8 + mlane)); \
    rw[16] = hastail ? *(const uint_t*)(src_ + 2*(128 + mlane)) : 0u; \
  }while(0)

#define CSTORE() do{ \
    _Pragma("unroll") \
    for (int j=0;j<16;++j){ \
      float a_, b_; unpack2(rw[j], a_, b_); \
      const int m_ = 2*(j*8 + mlane); \
      kpT[(m_  )*34 + rloc] = f2bf(RATIO*(__expf(a_ - g) + KEPS)); \
      kpT[(m_+1)*34 + rloc] = f2bf(RATIO*(__expf(b_ - g) + KEPS)); \
    } \
    if (hastail){ \
      float a_, b_; unpack2(rw[16], a_, b_); \
      const int m_ = 2*(128 + mlane); \
      kpT[(m_  )*34 + rloc] = f2bf(RATIO*(__expf(a_ - g) + KEPS)); \
      kpT[(m_+1)*34 + rloc] = f2bf(RATIO*(__expf(b_ - g) + KEPS)); \
    } \
  }while(0)

  f32x4 acc[17];
  #pragma unroll
  for (int i=0;i<17;++i) acc[i] = (f32x4){0.f,0.f,0.f,0.f};
  float zacc = 0.f, zacc2 = 0.f;
  const bool hasz2 = (256 + t) < MM;

  CLOAD(0);
  for (int ks=0; ks<4; ++ks){
    __syncthreads();
    CSTORE();
    __syncthreads();
    if (ks < 3) CLOAD(ks+1);

    {
      float s1 = 0.f;
      #pragma unroll
      for (int j=0;j<16;++j){
        float a_, b_; unpack2(*(const uint_t*)(kpT + t*34 + 2*j), a_, b_);
        s1 += a_; s1 += b_;
      }
      zacc += s1;
      if (t < 16){
        float s2 = 0.f;
        #pragma unroll
        for (int j=0;j<16;++j){
          float a_, b_; unpack2(*(const uint_t*)(kpT + (256+t)*34 + 2*j), a_, b_);
          s2 += a_; s2 += b_;
        }
        zacc2 += s2;
      }
    }
    bf16x8 bv = frag_ld(vT, 136, wv*16, ks*32);
    #pragma unroll
    for (int mt=0; mt<17; ++mt){
      bf16x8 a = frag_ld(kpT, 34, mt*16, 0);
      acc[mt] = mfma16(a, bv, acc[mt]);
    }
  }

  ushort_t* cg = ctx + (size_t)blk*MM*DD;
  const int e = wv*16 + (l&15);
  #pragma unroll
  for (int mt=0; mt<17; ++mt){
    #pragma unroll
    for (int r=0;r<4;++r){
      int m = mt*16 + ((l>>4)<<2) + r;
      if (m < MM) cg[(size_t)m*DD + e] = f2bf(acc[mt][r]);
    }
  }
  float* zgo = z + (size_t)blk*MM;
  zgo[t] = zacc;
  if (hasz2) zgo[256+t] = zacc2;
#undef CLOAD
#undef CSTORE
}

// ---------------- exclusive prefix over chunks (batched; ctx bf16, f32 accumulate) ----------------

__global__ __launch_bounds__(256) void k_prefix_ctx2(ushort_t* __restrict__ ctx){
  int blk = blockIdx.x; int bh = blk/67, mg = blk%67;
  int t = threadIdx.x; int mo = t>>6, e = t&63;
  int m = mg*4 + mo;
  if (m >= MM) return;
  size_t base = (size_t)bh*NCH*MM*DD + (size_t)m*DD + e;
  float vals[32];
  #pragma unroll
  for (int c=0;c<NCH;++c) vals[c] = bf2f(ctx[base + (size_t)c*MM*DD]);
  float run = 0.f;
  #pragma unroll
  for (int c=0;c<NCH;++c){
    float cur = vals[c];
    ctx[base + (size_t)c*MM*DD] = f2bf(run);
    run += cur;
  }
}

__global__ __launch_bounds__(256) void k_prefix_z2(float* __restrict__ z){
  int bh = blockIdx.x, t = threadIdx.x;
  size_t base = (size_t)bh*NCH*MM;
  {
    float va[32];
    #pragma unroll
    for (int c=0;c<NCH;++c) va[c] = z[base + (size_t)c*MM + t];
    float run = 0.f;
    #pragma unroll
    for (int c=0;c<NCH;++c){ float cur = va[c]; z[base + (size_t)c*MM + t] = run; run += cur; }
  }
  if (256 + t < MM){
    float vb[32];
    #pragma unroll
    for (int c=0;c<NCH;++c) vb[c] = z[base + (size_t)c*MM + 256 + t];
    float run = 0.f;
    #pragma unroll
    for (int c=0;c<NCH;++c){ float cur = vb[c]; z[base + (size_t)c*MM + 256 + t] = run; run += cur; }
  }
}

// ---------------- per-chunk output: 512 threads, z as 5th ctx e-tile (R8-verified) ----------------
// acc[8]=32 + oacc[5]=20 AGPR + ~100 VGPR -> no cap needed (R7/R10 lesson). LDS 52,224 -> 3 blocks/CU.

__global__ __launch_bounds__(512) void k_output10(const ushort_t* __restrict__ qp,
                                                  const ushort_t* __restrict__ kd,
                                                  const float* __restrict__ v,
                                                  const ushort_t* __restrict__ ctx,
                                                  const float* __restrict__ z,
                                                  const float* __restrict__ gmaxp,
                                                  float* __restrict__ out){
  __shared__ __align__(16) char lds[52224];
  ushort_t* qs   = (ushort_t*)lds;            // [128][72]  18,432 B
  ushort_t* kss  = (ushort_t*)(lds + 18432);  // [128][72]  18,432 B
  ushort_t* Ps   = (ushort_t*)lds;            // [128][136] 34,816 B (aliases qs+kss)
  ushort_t* ctxT = (ushort_t*)(lds + 36864);  // [80][72]   11,520 B (e-major; e=64 is z, 65..79 zero)
  ushort_t* vT   = (ushort_t*)(lds + 34816);  // [64][136]  17,408 B (after Ps end; post m-loop)

  const int blk = blockIdx.x, bh = blk>>5, ch = blk&31;
  const int t = threadIdx.x, l = t&63, wv = t>>6;   // wv in 0..7
  const int row0 = ch*CCH;
  const int wr0 = wv*16;                            // wave owns rows wr0..wr0+15
  const float g = gmaxp[0];

  const ushort_t* qg = qp + (size_t)(bh*NSEQ + row0)*MM;
  const ushort_t* kg = kd + (size_t)(bh*NSEQ + row0)*MM;
  const float*    vg = v  + (size_t)(bh*NSEQ + row0)*DD;
  const ushort_t* ctxg = ctx + (size_t)blk*MM*DD;
  const float*    zg = z  + (size_t)blk*MM;

  // register prefetch state
  const int mcol  = (t&31)<<1;   // q/k: m-offset within 64-tile (uint granularity)
  const int qrow0 = t>>5;        // q/k: rows qrow0 + 16i (qrow0 in 0..15)
  const int ce    = t&63;        // ctx: e
  const int cm0   = t>>6;        // ctx: mm = cm0 + 8i (cm0 in 0..7)
  uint_t rq[8], rk[8];
  ushort_t rc[8];
  float rz;

#define LOADREGS(MT) do{ \
    const int m0_ = (MT)*64; \
    const bool vq_ = (m0_ + mcol) < MM; \
    _Pragma("unroll") \
    for (int i=0;i<8;++i){ \
      int row_ = qrow0 + 16*i; \
      rq[i] = vq_ ? *(const uint_t*)(qg + (size_t)row_*MM + m0_ + mcol) : 0u; \
      rk[i] = vq_ ? *(const uint_t*)(kg + (size_t)row_*MM + m0_ + mcol) : 0u; \
    } \
    _Pragma("unroll") \
    for (int i=0;i<8;++i){ \
      int mm_ = cm0 + 8*i; \
      rc[i] = (m0_ + mm_ < MM) ? ctxg[(size_t)(m0_ + mm_)*DD + ce] : (ushort_t)0; \
    } \
    rz = (m0_ + (t&63) < MM) ? zg[m0_ + (t&63)] : 0.f; \
  }while(0)

#define WRITELDS(MT) do{ \
    const int m0_ = (MT)*64; \
    const bool vq_ = (m0_ + mcol) < MM; \
    _Pragma("unroll") \
    for (int i=0;i<8;++i){ \
      int row_ = qrow0 + 16*i; \
      *(uint_t*)(qs + row_*72 + mcol) = rq[i]; \
      uint_t ko_ = 0u; \
      if (vq_){ \
        float a_, b_; unpack2(rk[i], a_, b_); \
        a_ = RATIO*(__expf(a_ - g) + KEPS); \
        b_ = RATIO*(__expf(b_ - g) + KEPS); \
        ko_ = (uint_t)f2bf(a_) | ((uint_t)f2bf(b_)<<16); \
      } \
      *(uint_t*)(kss + row_*72 + mcol) = ko_; \
    } \
    _Pragma("unroll") \
    for (int i=0;i<8;++i) ctxT[ce*72 + cm0 + 8*i] = rc[i]; \
    if (t < 64) ctxT[64*72 + t] = f2bf(rz); \
  }while(0)

  // zero the ctxT pad e-rows 65..79 once (never rewritten)
  for (int idx=t; idx<15*72; idx+=512) ctxT[65*72 + idx] = 0;

  f32x4 acc[8];
  f32x4 oacc[5];
  #pragma unroll
  for (int ct=0;ct<8;++ct) acc[ct] = (f32x4){0.f,0.f,0.f,0.f};
  #pragma unroll
  for (int et=0;et<5;++et) oacc[et] = (f32x4){0.f,0.f,0.f,0.f};

  LOADREGS(0);
  for (int mt=0; mt<5; ++mt){
    __syncthreads();                  // readers of previous tile done (pad-zero visible at mt=0)
    WRITELDS(mt);
    __syncthreads();
    if (mt < 4) LOADREGS(mt+1);       // overlaps MFMA below

    bf16x8 aq[2];
    aq[0] = frag_ld(qs, 72, wr0, 0);
    aq[1] = frag_ld(qs, 72, wr0, 32);
    #pragma unroll
    for (int ct=0;ct<8;++ct){
      bf16x8 b0 = frag_ld(kss, 72, ct*16, 0);
      bf16x8 b1 = frag_ld(kss, 72, ct*16, 32);
      acc[ct] = mfma16(aq[0], b0, acc[ct]);
      acc[ct] = mfma16(aq[1], b1, acc[ct]);
    }
    #pragma unroll
    for (int et=0;et<5;++et){
      bf16x8 b0 = frag_ld(ctxT, 72, et*16, 0);
      bf16x8 b1 = frag_ld(ctxT, 72, et*16, 32);
      oacc[et] = mfma16(aq[0], b0, oacc[et]);
      oacc[et] = mfma16(aq[1], b1, oacc[et]);
    }
  }
  __syncthreads();  // all MFMA readers done before Ps/vT overwrite qs/kss/ctxT

  // issue V loads early (row-pairs; latency hides under mask/pack VALU below)
  float rv[16];
  const int rp = t>>6;   // == wv, 0..7; pair index rp+8i
  {
    #pragma unroll
    for (int i=0;i<8;++i){
      rv[2*i]   = vg[(size_t)(2*(rp+8*i)  )*DD + ce];
      rv[2*i+1] = vg[(size_t)(2*(rp+8*i)+1)*DD + ce];
    }
  }

  // ---- mask + row-sum + write P (bf16) to LDS ----
  float ds[4] = {0.f,0.f,0.f,0.f};
  #pragma unroll
  for (int ct=0;ct<8;++ct){
    #pragma unroll
    for (int r=0;r<4;++r){
      int i = wr0 + ((l>>4)<<2) + r;
      int j = ct*16 + (l&15);
      float m = (j <= i) ? acc[ct][r] : 0.f;
      acc[ct][r] = m;
      ds[r] += m;
    }
  }
  #pragma unroll
  for (int ct=0;ct<8;++ct){
    #pragma unroll
    for (int r=0;r<4;++r){
      int i = wr0 + ((l>>4)<<2) + r;
      Ps[i*136 + ct*16 + (l&15)] = f2bf(acc[ct][r]);
    }
  }
  // full D per lane: masked-S rowsum + z-dot from MFMA e-column 64 (lane l&48 holds col 0)
  float dtot[4];
  #pragma unroll
  for (int r=0;r<4;++r){
    float d = ds[r];
    d += __shfl_xor(d,1); d += __shfl_xor(d,2); d += __shfl_xor(d,4); d += __shfl_xor(d,8);
    dtot[r] = d + __shfl(oacc[4][r], l & 48);
  }
  // write V (transposed bf16, pair-packed uints) into region after Ps
  {
    #pragma unroll
    for (int i=0;i<8;++i)
      *(uint_t*)(vT + ce*136 + 2*(rp+8*i)) =
        (uint_t)f2bf(rv[2*i]) | ((uint_t)f2bf(rv[2*i+1])<<16);
  }
  __syncthreads();

  // ---- PV: oacc += P V ----
  #pragma unroll
  for (int kt=0;kt<4;++kt){
    bf16x8 ap = frag_ld(Ps, 136, wr0, kt*32);
    #pragma unroll
    for (int et=0;et<4;++et){
      bf16x8 bv = frag_ld(vT, 136, et*16, kt*32);
      oacc[et] = mfma16(ap, bv, oacc[et]);
    }
  }

  // ---- epilogue ----
  float* og = out + (size_t)(bh*NSEQ + row0)*DD;
  #pragma unroll
  for (int r=0;r<4;++r){
    int i = wr0 + ((l>>4)<<2) + r;
    float dinv = 1.0f / dtot[r];
    #pragma unroll
    for (int et=0;et<4;++et)
      og[(size_t)i*DD + et*16 + (l&15)] = oacc[et][r] * dinv;
  }
#undef LOADREGS
#undef WRITELDS
}

// ---------------- launch ----------------

extern "C" void kernel_launch(void* const* d_in, const int* in_sizes, int n_in,
                              void* d_out, int out_size, void* d_ws, size_t ws_size,
                              hipStream_t stream) {
  const float* q    = (const float*)d_in[0];
  const float* k    = (const float*)d_in[1];
  const float* v    = (const float*)d_in[2];
  const float* proj = (const float*)d_in[3];
  float* out = (float*)d_out;
  char* ws = (char*)d_ws;

  const size_t QP_OFF   = 0;             // bf16 [rows][266]  final qp
  const size_t KD_OFF   = 69730304ull;   // bf16 [rows][266]  s'_k (pre-exp)
  const size_t CTX_OFF  = 139460608ull;  // bf16 [1024][266][64] = 34,865,152
  const size_t Z_OFF    = 174325760ull;  // f32  [1024][266] = 1,089,536
  const size_t RSUB_OFF = 175415296ull;  // f32  [rows] = 524,288
  const size_t PART_OFF = 175939584ull;  // f32  [512]
  const size_t GMAX_OFF = 175941632ull;  // f32  [1]
  if (ws_size < 175942000ull) return;

  ushort_t* qp   = (ushort_t*)(ws + QP_OFF);
  ushort_t* kd   = (ushort_t*)(ws + KD_OFF);
  ushort_t* ctx  = (ushort_t*)(ws + CTX_OFF);
  float* z       = (float*)(ws + Z_OFF);
  float* rowsub  = (float*)(ws + RSUB_OFF);
  float* part    = (float*)(ws + PART_OFF);
  float* gmax    = (float*)(ws + GMAX_OFF);

  k_dashq2 <<<NROWS/128, 256, 0, stream>>>(q, proj, qp);
  k_dashk  <<<NROWS/128, 256, 0, stream>>>(k, proj, kd, rowsub);
  k_gmax1  <<<512, 256, 0, stream>>>(rowsub, part);
  k_gmax2  <<<1, 256, 0, stream>>>(part, gmax);
  k_chunksum5 <<<NBH*NCH, 256, 0, stream>>>(kd, v, gmax, ctx, z);
  k_prefix_ctx2<<<NBH*67, 256, 0, stream>>>(ctx);
  k_prefix_z2 <<<NBH, 256, 0, stream>>>(z);
  k_output10  <<<NBH*NCH, 512, 0, stream>>>(qp, kd, v, ctx, z, gmax, out);
}

// Round 17
// 199.049 us; speedup vs baseline: 1.3074x; 1.0236x over previous
//
#include <hip/hip_runtime.h>

#define BB 4
#define HH 8
#define NSEQ 4096
#define DD 64
#define MM 266
#define CCH 128
#define NCH 32
#define NBH (BB*HH)
#define NROWS (NBH*NSEQ)

#define NORMALIZER 0.35355339059327373f
#define DIAGF 0.0625f
#define RATIO 0.0613140017f
#define KEPS 1e-4f
#define SBIAS 4.0f

typedef unsigned short ushort_t;
typedef unsigned int uint_t;

typedef __attribute__((ext_vector_type(8))) short bf16x8;
typedef __attribute__((ext_vector_type(4))) float f32x4;

__device__ __forceinline__ f32x4 mfma16(bf16x8 a, bf16x8 b, f32x4 c){
  return __builtin_amdgcn_mfma_f32_16x16x32_bf16(a, b, c, 0, 0, 0);
}

__device__ __forceinline__ ushort_t f2bf(float x){
  union { float f; uint_t u; } v; v.f = x;
  uint_t r = (v.u + 0x7FFFu + ((v.u >> 16) & 1u)) >> 16;
  return (ushort_t)r;
}
__device__ __forceinline__ float bf2f(ushort_t h){
  union { uint_t u; float f; } v; v.u = ((uint_t)h) << 16;
  return v.f;
}
__device__ __forceinline__ void unpack2(uint_t w, float& lo, float& hi){
  union { uint_t u; float f; } a, b;
  a.u = w << 16; b.u = w & 0xFFFF0000u;
  lo = a.f; hi = b.f;
}

// monotonic float<->uint for atomicMax-based global max
__device__ __forceinline__ uint_t fenc(float f){
  uint_t b = __float_as_uint(f);
  return (b & 0x80000000u) ? ~b : (b | 0x80000000u);
}
__device__ __forceinline__ float fdec(uint_t u){
  uint_t b = (u >> 31) ? (u ^ 0x80000000u) : ~u;
  return __uint_as_float(b);
}

// MFMA fragment load from a row-major LDS tile.
// lane l supplies element [spatial = s0 + (l&15)][k = koff + (l>>4)*8 + j], j=0..7
// NOTE (R14 lesson): strides whose byte size is not 0 mod 16 split every ds_*_b128
// and cost ~2x. 72 and 136 ushorts are the verified-aligned choices.
__device__ __forceinline__ bf16x8 frag_ld(const ushort_t* tile, int stride, int s0, int koff){
  const int l = threadIdx.x & 63;
  return *(const bf16x8*)(tile + (s0 + (l&15))*stride + koff + ((l>>4)<<3));
}

// ---------------- q projection: pass1 MFMA dash -> s' kept bf16-packed in regs;
// pass2 = exp+store only. Also inits the gmax atomic cell (runs before k_dashk2). ----------------

__global__ __launch_bounds__(256) void k_dashq2(const float* __restrict__ x,
                                                const float* __restrict__ proj,
                                                ushort_t* __restrict__ qp,
                                                uint_t* __restrict__ gmaxu){
  if (blockIdx.x==0 && threadIdx.x==0) gmaxu[0] = 0u;  // encoded floor (below any real max)

  __shared__ __align__(16) ushort_t pjs[272*72];
  __shared__ __align__(16) ushort_t qs[128*72];
  __shared__ float diags[128];
  const int t = threadIdx.x;

  #pragma unroll
  for (int h=0; h<2; ++h){
    float2 pv[17];
    #pragma unroll
    for (int i=0;i<17;++i){
      int idx = t + (h*17+i)*256;
      int m = idx>>5, dp = (idx&31)*2;
      float2 p2 = {0.f,0.f};
      if (m < MM) p2 = *(const float2*)(proj + (size_t)m*DD + dp);
      pv[i] = p2;
    }
    #pragma unroll
    for (int i=0;i<17;++i){
      int idx = t + (h*17+i)*256;
      int m = idx>>5, dp = (idx&31)*2;
      *(uint_t*)(pjs + m*72 + dp) = (uint_t)f2bf(pv[i].x) | ((uint_t)f2bf(pv[i].y)<<16);
    }
  }
  {
    const int row = t>>1, half = t&1;
    const float2* xr = (const float2*)(x + ((size_t)blockIdx.x*128 + row)*DD + half*32);
    float ss = 0.f;
    #pragma unroll
    for (int i=0;i<16;++i){
      float2 a = xr[i];
      ss += a.x*a.x + a.y*a.y;
      uint_t w = (uint_t)f2bf(a.x*NORMALIZER) | ((uint_t)f2bf(a.y*NORMALIZER)<<16);
      *(uint_t*)(qs + row*72 + half*32 + i*2) = w;
    }
    ss += __shfl_xor(ss, 1);
    if (half==0) diags[row] = ss*DIAGF;
  }
  __syncthreads();

  const int l = t&63, wv = t>>6;
  const int wr0 = wv*32;
  float dv[2][4];
  #pragma unroll
  for (int rt=0;rt<2;++rt)
    #pragma unroll
    for (int r=0;r<4;++r) dv[rt][r] = diags[wr0 + rt*16 + ((l>>4)<<2) + r];

  float rmax[2][4];
  #pragma unroll
  for (int rt=0;rt<2;++rt){ rmax[rt][0]=-3e38f; rmax[rt][1]=-3e38f; rmax[rt][2]=-3e38f; rmax[rt][3]=-3e38f; }
  uint_t spu[17][2][2];
  #pragma unroll
  for (int mt=0; mt<17; ++mt){
    bf16x8 b0 = frag_ld(pjs, 72, mt*16, 0);
    bf16x8 b1 = frag_ld(pjs, 72, mt*16, 32);
    const bool valid = (mt*16 + (l&15)) < MM;
    #pragma unroll
    for (int rt=0;rt<2;++rt){
      bf16x8 a0 = frag_ld(qs, 72, wr0+rt*16, 0);
      bf16x8 a1 = frag_ld(qs, 72, wr0+rt*16, 32);
      f32x4 acc = {0.f,0.f,0.f,0.f};
      acc = mfma16(a0, b0, acc);
      acc = mfma16(a1, b1, acc);
      float sp0 = acc[0]-dv[rt][0]+SBIAS, sp1 = acc[1]-dv[rt][1]+SBIAS;
      float sp2 = acc[2]-dv[rt][2]+SBIAS, sp3 = acc[3]-dv[rt][3]+SBIAS;
      if (valid){
        rmax[rt][0] = fmaxf(rmax[rt][0], sp0); rmax[rt][1] = fmaxf(rmax[rt][1], sp1);
        rmax[rt][2] = fmaxf(rmax[rt][2], sp2); rmax[rt][3] = fmaxf(rmax[rt][3], sp3);
      }
      spu[mt][rt][0] = (uint_t)f2bf(sp0) | ((uint_t)f2bf(sp1)<<16);
      spu[mt][rt][1] = (uint_t)f2bf(sp2) | ((uint_t)f2bf(sp3)<<16);
    }
  }
  float sub[2][4];
  #pragma unroll
  for (int rt=0;rt<2;++rt){
    #pragma unroll
    for (int r=0;r<4;++r){
      float m = rmax[rt][r];
      m = fmaxf(m, __shfl_xor(m,1)); m = fmaxf(m, __shfl_xor(m,2));
      m = fmaxf(m, __shfl_xor(m,4)); m = fmaxf(m, __shfl_xor(m,8));
      // sub = max(s') + diag; the +diag is REQUIRED (R6 failure: eps does not cancel)
      sub[rt][r] = m + dv[rt][r];
    }
  }

  const size_t growb = (size_t)blockIdx.x*128;
  #pragma unroll
  for (int mt=0; mt<17; ++mt){
    const int m = mt*16 + (l&15);
    if (m < MM){
      #pragma unroll
      for (int rt=0;rt<2;++rt){
        float a0,a1,a2,a3;
        unpack2(spu[mt][rt][0], a0, a1);
        unpack2(spu[mt][rt][1], a2, a3);
        const size_t rb = growb + wr0 + rt*16 + ((l>>4)<<2);
        qp[(rb+0)*MM + m] = f2bf(RATIO*(__expf(a0 - sub[rt][0]) + KEPS));
        qp[(rb+1)*MM + m] = f2bf(RATIO*(__expf(a1 - sub[rt][1]) + KEPS));
        qp[(rb+2)*MM + m] = f2bf(RATIO*(__expf(a2 - sub[rt][2]) + KEPS));
        qp[(rb+3)*MM + m] = f2bf(RATIO*(__expf(a3 - sub[rt][3]) + KEPS));
      }
    }
  }
}

// ---------------- k dash: s' stored bf16; block max -> device atomicMax(gmax) ----------------

__global__ __launch_bounds__(256) void k_dashk2(const float* __restrict__ x,
                                                const float* __restrict__ proj,
                                                ushort_t* __restrict__ sbuf,
                                                uint_t* __restrict__ gmaxu){
  __shared__ __align__(16) ushort_t pjs[272*72];
  __shared__ __align__(16) ushort_t qs[128*72];
  __shared__ float diags[128];
  __shared__ float smax[4];
  const int t = threadIdx.x;

  #pragma unroll
  for (int h=0; h<2; ++h){
    float2 pv[17];
    #pragma unroll
    for (int i=0;i<17;++i){
      int idx = t + (h*17+i)*256;
      int m = idx>>5, dp = (idx&31)*2;
      float2 p2 = {0.f,0.f};
      if (m < MM) p2 = *(const float2*)(proj + (size_t)m*DD + dp);
      pv[i] = p2;
    }
    #pragma unroll
    for (int i=0;i<17;++i){
      int idx = t + (h*17+i)*256;
      int m = idx>>5, dp = (idx&31)*2;
      *(uint_t*)(pjs + m*72 + dp) = (uint_t)f2bf(pv[i].x) | ((uint_t)f2bf(pv[i].y)<<16);
    }
  }
  {
    const int row = t>>1, half = t&1;
    const float2* xr = (const float2*)(x + ((size_t)blockIdx.x*128 + row)*DD + half*32);
    float ss = 0.f;
    #pragma unroll
    for (int i=0;i<16;++i){
      float2 a = xr[i];
      ss += a.x*a.x + a.y*a.y;
      uint_t w = (uint_t)f2bf(a.x*NORMALIZER) | ((uint_t)f2bf(a.y*NORMALIZER)<<16);
      *(uint_t*)(qs + row*72 + half*32 + i*2) = w;
    }
    ss += __shfl_xor(ss, 1);
    if (half==0) diags[row] = ss*DIAGF;
  }
  __syncthreads();

  const int l = t&63, wv = t>>6;
  const int wr0 = wv*32;
  float dv[2][4];
  #pragma unroll
  for (int rt=0;rt<2;++rt)
    #pragma unroll
    for (int r=0;r<4;++r) dv[rt][r] = diags[wr0 + rt*16 + ((l>>4)<<2) + r];

  float rmax[2][4];
  #pragma unroll
  for (int rt=0;rt<2;++rt){ rmax[rt][0]=-3e38f; rmax[rt][1]=-3e38f; rmax[rt][2]=-3e38f; rmax[rt][3]=-3e38f; }

  const size_t growb = (size_t)blockIdx.x*128;
  for (int mt=0; mt<17; ++mt){
    bf16x8 b0 = frag_ld(pjs, 72, mt*16, 0);
    bf16x8 b1 = frag_ld(pjs, 72, mt*16, 32);
    const int m = mt*16 + (l&15);
    const bool valid = (m < MM);
    #pragma unroll
    for (int rt=0;rt<2;++rt){
      bf16x8 a0 = frag_ld(qs, 72, wr0+rt*16, 0);
      bf16x8 a1 = frag_ld(qs, 72, wr0+rt*16, 32);
      f32x4 acc = {0.f,0.f,0.f,0.f};
      acc = mfma16(a0, b0, acc);
      acc = mfma16(a1, b1, acc);
      #pragma unroll
      for (int r=0;r<4;++r){
        float sp = acc[r] - dv[rt][r] + SBIAS;
        if (valid){
          rmax[rt][r] = fmaxf(rmax[rt][r], sp);
          sbuf[(growb + wr0 + rt*16 + ((l>>4)<<2) + r)*MM + m] = f2bf(sp);
        }
      }
    }
  }
  // block max of (rowmax(s') + diag) = rowmax(dash)+SBIAS; one device-scope atomic per block.
  float bm = -3e38f;
  #pragma unroll
  for (int rt=0;rt<2;++rt){
    #pragma unroll
    for (int r=0;r<4;++r){
      float m = rmax[rt][r];
      m = fmaxf(m, __shfl_xor(m,1)); m = fmaxf(m, __shfl_xor(m,2));
      m = fmaxf(m, __shfl_xor(m,4)); m = fmaxf(m, __shfl_xor(m,8));
      bm = fmaxf(bm, m + dv[rt][r]);
    }
  }
  bm = fmaxf(bm, __shfl_xor(bm,16));
  bm = fmaxf(bm, __shfl_xor(bm,32));
  if (l==0) smax[wv] = bm;
  __syncthreads();
  if (t==0){
    float g = fmaxf(fmaxf(smax[0],smax[1]), fmaxf(smax[2],smax[3]));
    atomicMax(gmaxu, fenc(g));
  }
}

// ---------------- chunk sums via MFMA; b32 colsum + pair-packed vT staging (R15 body) ----------------

__global__ __launch_bounds__(256) void k_chunksum5(const ushort_t* __restrict__ kd,
                                                   const float* __restrict__ v,
                                                   const uint_t* __restrict__ gmaxu,
                                                   ushort_t* __restrict__ ctx,
                                                   float* __restrict__ z){
  __shared__ __align__(16) ushort_t kpT[272*34];  // [m][row-subtile 32]
  __shared__ __align__(16) ushort_t vT[64*136];   // [e][row 128]
  const int blk = blockIdx.x, bh = blk>>5, ch = blk&31;
  const int t = threadIdx.x, l = t&63, wv = t>>6;
  const int row0 = ch*CCH;
  const ushort_t* kg = kd + (size_t)(bh*NSEQ + row0)*MM;
  const float*    vg = v  + (size_t)(bh*NSEQ + row0)*DD;
  const float g = fdec(gmaxu[0]);

  // stage V transposed: row-pairs packed as uints
  {
    const int e = t&63, rp = t>>6;
    float rv[32];
    #pragma unroll
    for (int i=0;i<16;++i){
      rv[2*i]   = vg[(size_t)(2*(rp+4*i)  )*DD + e];
      rv[2*i+1] = vg[(size_t)(2*(rp+4*i)+1)*DD + e];
    }
    #pragma unroll
    for (int i=0;i<16;++i)
      *(uint_t*)(vT + e*136 + 2*(rp+4*i)) =
        (uint_t)f2bf(rv[2*i]) | ((uint_t)f2bf(rv[2*i+1])<<16);
  }
  // zero-fill pad m-rows 266..271 once
  for (int idx=t; idx<6*34; idx+=256) kpT[266*34 + idx] = 0;

  const int rloc  = t>>3;
  const int mlane = t&7;
  const bool hastail = (mlane < 5);
  uint_t rw[17];

#define CLOAD(KS) do{ \
    const ushort_t* src_ = kg + (size_t)((KS)*32 + rloc)*MM; \
    _Pragma("unroll") \
    for (int j=0;j<16;++j) rw[j] = *(const uint_t*)(src_ + 2*(j*8 + mlane)); \
    rw[16] = hastail ? *(const uint_t*)(src_ + 2*(128 + mlane)) : 0u; \
  }while(0)

#define CSTORE() do{ \
    _Pragma("unroll") \
    for (int j=0;j<16;++j){ \
      float a_, b_; unpack2(rw[j], a_, b_); \
      const int m_ = 2*(j*8 + mlane); \
      kpT[(m_  )*34 + rloc] = f2bf(RATIO*(__expf(a_ - g) + KEPS)); \
      kpT[(m_+1)*34 + rloc] = f2bf(RATIO*(__expf(b_ - g) + KEPS)); \
    } \
    if (hastail){ \
      float a_, b_; unpack2(rw[16], a_, b_); \
      const int m_ = 2*(128 + mlane); \
      kpT[(m_  )*34 + rloc] = f2bf(RATIO*(__expf(a_ - g) + KEPS)); \
      kpT[(m_+1)*34 + rloc] = f2bf(RATIO*(__expf(b_ - g) + KEPS)); \
    } \
  }while(0)

  f32x4 acc[17];
  #pragma unroll
  for (int i=0;i<17;++i) acc[i] = (f32x4){0.f,0.f,0.f,0.f};
  float zacc = 0.f, zacc2 = 0.f;
  const bool hasz2 = (256 + t) < MM;

  CLOAD(0);
  for (int ks=0; ks<4; ++ks){
    __syncthreads();
    CSTORE();
    __syncthreads();
    if (ks < 3) CLOAD(ks+1);

    {
      float s1 = 0.f;
      #pragma unroll
      for (int j=0;j<16;++j){
        float a_, b_; unpack2(*(const uint_t*)(kpT + t*34 + 2*j), a_, b_);
        s1 += a_; s1 += b_;
      }
      zacc += s1;
      if (t < 16){
        float s2 = 0.f;
        #pragma unroll
        for (int j=0;j<16;++j){
          float a_, b_; unpack2(*(const uint_t*)(kpT + (256+t)*34 + 2*j), a_, b_);
          s2 += a_; s2 += b_;
        }
        zacc2 += s2;
      }
    }
    bf16x8 bv = frag_ld(vT, 136, wv*16, ks*32);
    #pragma unroll
    for (int mt=0; mt<17; ++mt){
      bf16x8 a = frag_ld(kpT, 34, mt*16, 0);
      acc[mt] = mfma16(a, bv, acc[mt]);
    }
  }

  ushort_t* cg = ctx + (size_t)blk*MM*DD;
  const int e = wv*16 + (l&15);
  #pragma unroll
  for (int mt=0; mt<17; ++mt){
    #pragma unroll
    for (int r=0;r<4;++r){
      int m = mt*16 + ((l>>4)<<2) + r;
      if (m < MM) cg[(size_t)m*DD + e] = f2bf(acc[mt][r]);
    }
  }
  float* zgo = z + (size_t)blk*MM;
  zgo[t] = zacc;
  if (hasz2) zgo[256+t] = zacc2;
#undef CLOAD
#undef CSTORE
}

// ---------------- fused exclusive prefixes (ctx bf16 + z f32) ----------------

__global__ __launch_bounds__(256) void k_prefix3(ushort_t* __restrict__ ctx,
                                                 float* __restrict__ z){
  int bid = blockIdx.x;
  if (bid < NBH*67){
    int bh = bid/67, mg = bid%67;
    int t = threadIdx.x; int mo = t>>6, e = t&63;
    int m = mg*4 + mo;
    if (m >= MM) return;
    size_t base = (size_t)bh*NCH*MM*DD + (size_t)m*DD + e;
    float vals[32];
    #pragma unroll
    for (int c=0;c<NCH;++c) vals[c] = bf2f(ctx[base + (size_t)c*MM*DD]);
    float run = 0.f;
    #pragma unroll
    for (int c=0;c<NCH;++c){
      float cur = vals[c];
      ctx[base + (size_t)c*MM*DD] = f2bf(run);
      run += cur;
    }
  } else {
    int bh = bid - NBH*67, t = threadIdx.x;
    size_t base = (size_t)bh*NCH*MM;
    {
      float va[32];
      #pragma unroll
      for (int c=0;c<NCH;++c) va[c] = z[base + (size_t)c*MM + t];
      float run = 0.f;
      #pragma unroll
      for (int c=0;c<NCH;++c){ float cur = va[c]; z[base + (size_t)c*MM + t] = run; run += cur; }
    }
    if (256 + t < MM){
      float vb[32];
      #pragma unroll
      for (int c=0;c<NCH;++c) vb[c] = z[base + (size_t)c*MM + 256 + t];
      float run = 0.f;
      #pragma unroll
      for (int c=0;c<NCH;++c){ float cur = vb[c]; z[base + (size_t)c*MM + 256 + t] = run; run += cur; }
    }
  }
}

// ---------------- per-chunk output: 512 threads, z as 5th ctx e-tile (R8-verified) ----------------

__global__ __launch_bounds__(512) void k_output10(const ushort_t* __restrict__ qp,
                                                  const ushort_t* __restrict__ kd,
                                                  const float* __restrict__ v,
                                                  const ushort_t* __restrict__ ctx,
                                                  const float* __restrict__ z,
                                                  const uint_t* __restrict__ gmaxu,
                                                  float* __restrict__ out){
  __shared__ __align__(16) char lds[52224];
  ushort_t* qs   = (ushort_t*)lds;            // [128][72]  18,432 B
  ushort_t* kss  = (ushort_t*)(lds + 18432);  // [128][72]  18,432 B
  ushort_t* Ps   = (ushort_t*)lds;            // [128][136] 34,816 B (aliases qs+kss)
  ushort_t* ctxT = (ushort_t*)(lds + 36864);  // [80][72]   11,520 B (e-major; e=64 is z, 65..79 zero)
  ushort_t* vT   = (ushort_t*)(lds + 34816);  // [64][136]  17,408 B (after Ps end; post m-loop)

  const int blk = blockIdx.x, bh = blk>>5, ch = blk&31;
  const int t = threadIdx.x, l = t&63, wv = t>>6;   // wv in 0..7
  const int row0 = ch*CCH;
  const int wr0 = wv*16;                            // wave owns rows wr0..wr0+15
  const float g = fdec(gmaxu[0]);

  const ushort_t* qg = qp + (size_t)(bh*NSEQ + row0)*MM;
  const ushort_t* kg = kd + (size_t)(bh*NSEQ + row0)*MM;
  const float*    vg = v  + (size_t)(bh*NSEQ + row0)*DD;
  const ushort_t* ctxg = ctx + (size_t)blk*MM*DD;
  const float*    zg = z  + (size_t)blk*MM;

  // register prefetch state
  const int mcol  = (t&31)<<1;   // q/k: m-offset within 64-tile (uint granularity)
  const int qrow0 = t>>5;        // q/k: rows qrow0 + 16i (qrow0 in 0..15)
  const int ce    = t&63;        // ctx: e
  const int cm0   = t>>6;        // ctx: mm = cm0 + 8i (cm0 in 0..7)
  uint_t rq[8], rk[8];
  ushort_t rc[8];
  float rz;

#define LOADREGS(MT) do{ \
    const int m0_ = (MT)*64; \
    const bool vq_ = (m0_ + mcol) < MM; \
    _Pragma("unroll") \
    for (int i=0;i<8;++i){ \
      int row_ = qrow0 + 16*i; \
      rq[i] = vq_ ? *(const uint_t*)(qg + (size_t)row_*MM + m0_ + mcol) : 0u; \
      rk[i] = vq_ ? *(const uint_t*)(kg + (size_t)row_*MM + m0_ + mcol) : 0u; \
    } \
    _Pragma("unroll") \
    for (int i=0;i<8;++i){ \
      int mm_ = cm0 + 8*i; \
      rc[i] = (m0_ + mm_ < MM) ? ctxg[(size_t)(m0_ + mm_)*DD + ce] : (ushort_t)0; \
    } \
    rz = (m0_ + (t&63) < MM) ? zg[m0_ + (t&63)] : 0.f; \
  }while(0)

#define WRITELDS(MT) do{ \
    const int m0_ = (MT)*64; \
    const bool vq_ = (m0_ + mcol) < MM; \
    _Pragma("unroll") \
    for (int i=0;i<8;++i){ \
      int row_ = qrow0 + 16*i; \
      *(uint_t*)(qs + row_*72 + mcol) = rq[i]; \
      uint_t ko_ = 0u; \
      if (vq_){ \
        float a_, b_; unpack2(rk[i], a_, b_); \
        a_ = RATIO*(__expf(a_ - g) + KEPS); \
        b_ = RATIO*(__expf(b_ - g) + KEPS); \
        ko_ = (uint_t)f2bf(a_) | ((uint_t)f2bf(b_)<<16); \
      } \
      *(uint_t*)(kss + row_*72 + mcol) = ko_; \
    } \
    _Pragma("unroll") \
    for (int i=0;i<8;++i) ctxT[ce*72 + cm0 + 8*i] = rc[i]; \
    if (t < 64) ctxT[64*72 + t] = f2bf(rz); \
  }while(0)

  // zero the ctxT pad e-rows 65..79 once (never rewritten)
  for (int idx=t; idx<15*72; idx+=512) ctxT[65*72 + idx] = 0;

  f32x4 acc[8];
  f32x4 oacc[5];
  #pragma unroll
  for (int ct=0;ct<8;++ct) acc[ct] = (f32x4){0.f,0.f,0.f,0.f};
  #pragma unroll
  for (int et=0;et<5;++et) oacc[et] = (f32x4){0.f,0.f,0.f,0.f};

  LOADREGS(0);
  for (int mt=0; mt<5; ++mt){
    __syncthreads();                  // readers of previous tile done (pad-zero visible at mt=0)
    WRITELDS(mt);
    __syncthreads();
    if (mt < 4) LOADREGS(mt+1);       // overlaps MFMA below

    bf16x8 aq[2];
    aq[0] = frag_ld(qs, 72, wr0, 0);
    aq[1] = frag_ld(qs, 72, wr0, 32);
    #pragma unroll
    for (int ct=0;ct<8;++ct){
      bf16x8 b0 = frag_ld(kss, 72, ct*16, 0);
      bf16x8 b1 = frag_ld(kss, 72, ct*16, 32);
      acc[ct] = mfma16(aq[0], b0, acc[ct]);
      acc[ct] = mfma16(aq[1], b1, acc[ct]);
    }
    #pragma unroll
    for (int et=0;et<5;++et){
      bf16x8 b0 = frag_ld(ctxT, 72, et*16, 0);
      bf16x8 b1 = frag_ld(ctxT, 72, et*16, 32);
      oacc[et] = mfma16(aq[0], b0, oacc[et]);
      oacc[et] = mfma16(aq[1], b1, oacc[et]);
    }
  }
  __syncthreads();  // all MFMA readers done before Ps/vT overwrite qs/kss/ctxT

  // issue V loads early (row-pairs; latency hides under mask/pack VALU below)
  float rv[16];
  const int rp = t>>6;   // == wv, 0..7; pair index rp+8i
  {
    #pragma unroll
    for (int i=0;i<8;++i){
      rv[2*i]   = vg[(size_t)(2*(rp+8*i)  )*DD + ce];
      rv[2*i+1] = vg[(size_t)(2*(rp+8*i)+1)*DD + ce];
    }
  }

  // ---- mask + row-sum + write P (bf16) to LDS ----
  float ds[4] = {0.f,0.f,0.f,0.f};
  #pragma unroll
  for (int ct=0;ct<8;++ct){
    #pragma unroll
    for (int r=0;r<4;++r){
      int i = wr0 + ((l>>4)<<2) + r;
      int j = ct*16 + (l&15);
      float m = (j <= i) ? acc[ct][r] : 0.f;
      acc[ct][r] = m;
      ds[r] += m;
    }
  }
  #pragma unroll
  for (int ct=0;ct<8;++ct){
    #pragma unroll
    for (int r=0;r<4;++r){
      int i = wr0 + ((l>>4)<<2) + r;
      Ps[i*136 + ct*16 + (l&15)] = f2bf(acc[ct][r]);
    }
  }
  // full D per lane: masked-S rowsum + z-dot from MFMA e-column 64 (lane l&48 holds col 0)
  float dtot[4];
  #pragma unroll
  for (int r=0;r<4;++r){
    float d = ds[r];
    d += __shfl_xor(d,1); d += __shfl_xor(d,2); d += __shfl_xor(d,4); d += __shfl_xor(d,8);
    dtot[r] = d + __shfl(oacc[4][r], l & 48);
  }
  // write V (transposed bf16, pair-packed uints) into region after Ps
  {
    #pragma unroll
    for (int i=0;i<8;++i)
      *(uint_t*)(vT + ce*136 + 2*(rp+8*i)) =
        (uint_t)f2bf(rv[2*i]) | ((uint_t)f2bf(rv[2*i+1])<<16);
  }
  __syncthreads();

  // ---- PV: oacc += P V ----
  #pragma unroll
  for (int kt=0;kt<4;++kt){
    bf16x8 ap = frag_ld(Ps, 136, wr0, kt*32);
    #pragma unroll
    for (int et=0;et<4;++et){
      bf16x8 bv = frag_ld(vT, 136, et*16, kt*32);
      oacc[et] = mfma16(ap, bv, oacc[et]);
    }
  }

  // ---- epilogue ----
  float* og = out + (size_t)(bh*NSEQ + row0)*DD;
  #pragma unroll
  for (int r=0;r<4;++r){
    int i = wr0 + ((l>>4)<<2) + r;
    float dinv = 1.0f / dtot[r];
    #pragma unroll
    for (int et=0;et<4;++et)
      og[(size_t)i*DD + et*16 + (l&15)] = oacc[et][r] * dinv;
  }
#undef LOADREGS
#undef WRITELDS
}

// ---------------- launch ----------------

extern "C" void kernel_launch(void* const* d_in, const int* in_sizes, int n_in,
                              void* d_out, int out_size, void* d_ws, size_t ws_size,
                              hipStream_t stream) {
  const float* q    = (const float*)d_in[0];
  const float* k    = (const float*)d_in[1];
  const float* v    = (const float*)d_in[2];
  const float* proj = (const float*)d_in[3];
  float* out = (float*)d_out;
  char* ws = (char*)d_ws;

  const size_t QP_OFF   = 0;             // bf16 [rows][266]  final qp
  const size_t KD_OFF   = 69730304ull;   // bf16 [rows][266]  s'_k (pre-exp)
  const size_t CTX_OFF  = 139460608ull;  // bf16 [1024][266][64] = 34,865,152
  const size_t Z_OFF    = 174325760ull;  // f32  [1024][266] = 1,089,536
  const size_t GMAX_OFF = 175415296ull;  // uint [1] (monotonic-encoded float max)
  if (ws_size < 175416000ull) return;

  ushort_t* qp   = (ushort_t*)(ws + QP_OFF);
  ushort_t* kd   = (ushort_t*)(ws + KD_OFF);
  ushort_t* ctx  = (ushort_t*)(ws + CTX_OFF);
  float* z       = (float*)(ws + Z_OFF);
  uint_t* gmaxu  = (uint_t*)(ws + GMAX_OFF);

  k_dashq2   <<<NROWS/128, 256, 0, stream>>>(q, proj, qp, gmaxu);
  k_dashk2   <<<NROWS/128, 256, 0, stream>>>(k, proj, kd, gmaxu);
  k_chunksum5<<<NBH*NCH, 256, 0, stream>>>(kd, v, gmaxu, ctx, z);
  k_prefix3  <<<NBH*67 + NBH, 256, 0, stream>>>(ctx, z);
  k_output10 <<<NBH*NCH, 512, 0, stream>>>(qp, kd, v, ctx, z, gmaxu, out);
}

// Round 18
// 198.854 us; speedup vs baseline: 1.3087x; 1.0010x over previous
//
#include <hip/hip_runtime.h>

#define BB 4
#define HH 8
#define NSEQ 4096
#define DD 64
#define MM 266
#define CCH 128
#define NCH 32
#define NBH (BB*HH)
#define NROWS (NBH*NSEQ)

#define NORMALIZER 0.35355339059327373f
#define DIAGF 0.0625f
#define RATIO 0.0613140017f
#define KEPS 1e-4f
#define SBIAS 4.0f

typedef unsigned short ushort_t;
typedef unsigned int uint_t;

typedef __attribute__((ext_vector_type(8))) short bf16x8;
typedef __attribute__((ext_vector_type(4))) float f32x4;

__device__ __forceinline__ f32x4 mfma16(bf16x8 a, bf16x8 b, f32x4 c){
  return __builtin_amdgcn_mfma_f32_16x16x32_bf16(a, b, c, 0, 0, 0);
}

__device__ __forceinline__ ushort_t f2bf(float x){
  union { float f; uint_t u; } v; v.f = x;
  uint_t r = (v.u + 0x7FFFu + ((v.u >> 16) & 1u)) >> 16;
  return (ushort_t)r;
}
__device__ __forceinline__ float bf2f(ushort_t h){
  union { uint_t u; float f; } v; v.u = ((uint_t)h) << 16;
  return v.f;
}
__device__ __forceinline__ void unpack2(uint_t w, float& lo, float& hi){
  union { uint_t u; float f; } a, b;
  a.u = w << 16; b.u = w & 0xFFFF0000u;
  lo = a.f; hi = b.f;
}

// monotonic float<->uint for atomicMax-based global max (cell memset to 0 = floor)
__device__ __forceinline__ uint_t fenc(float f){
  uint_t b = __float_as_uint(f);
  return (b & 0x80000000u) ? ~b : (b | 0x80000000u);
}
__device__ __forceinline__ float fdec(uint_t u){
  uint_t b = (u >> 31) ? (u ^ 0x80000000u) : ~u;
  return __uint_as_float(b);
}

// MFMA fragment load from a row-major LDS tile.
// lane l supplies element [spatial = s0 + (l&15)][k = koff + (l>>4)*8 + j], j=0..7
// NOTE (R14 lesson): strides whose byte size is not 0 mod 16 split every ds_*_b128
// and cost ~2x. 72 and 136 ushorts are the verified-aligned choices.
__device__ __forceinline__ bf16x8 frag_ld(const ushort_t* tile, int stride, int s0, int koff){
  const int l = threadIdx.x & 63;
  return *(const bf16x8*)(tile + (s0 + (l&15))*stride + koff + ((l>>4)<<3));
}

// ---------------- fused dash kernel: blocks [0,1024) = q side, [1024,2048) = k side.
// Sides are independent; gmax cell is memset on the stream before launch. ----------------

__global__ __launch_bounds__(256) void k_dash_both(const float* __restrict__ q,
                                                   const float* __restrict__ k,
                                                   const float* __restrict__ proj,
                                                   ushort_t* __restrict__ qp,
                                                   ushort_t* __restrict__ kd,
                                                   uint_t* __restrict__ gmaxu){
  __shared__ __align__(16) ushort_t pjs[272*72];
  __shared__ __align__(16) ushort_t qs[128*72];
  __shared__ float diags[128];
  __shared__ float smax[4];
  const int t = threadIdx.x;
  const bool isq = blockIdx.x < (NROWS/128);
  const int blk = isq ? blockIdx.x : (blockIdx.x - NROWS/128);
  const float* x = isq ? q : k;

  // stage projection (batched)
  #pragma unroll
  for (int h=0; h<2; ++h){
    float2 pv[17];
    #pragma unroll
    for (int i=0;i<17;++i){
      int idx = t + (h*17+i)*256;
      int m = idx>>5, dp = (idx&31)*2;
      float2 p2 = {0.f,0.f};
      if (m < MM) p2 = *(const float2*)(proj + (size_t)m*DD + dp);
      pv[i] = p2;
    }
    #pragma unroll
    for (int i=0;i<17;++i){
      int idx = t + (h*17+i)*256;
      int m = idx>>5, dp = (idx&31)*2;
      *(uint_t*)(pjs + m*72 + dp) = (uint_t)f2bf(pv[i].x) | ((uint_t)f2bf(pv[i].y)<<16);
    }
  }
  // stage x rows (bf16, normalized) + diag
  {
    const int row = t>>1, half = t&1;
    const float2* xr = (const float2*)(x + ((size_t)blk*128 + row)*DD + half*32);
    float ss = 0.f;
    #pragma unroll
    for (int i=0;i<16;++i){
      float2 a = xr[i];
      ss += a.x*a.x + a.y*a.y;
      uint_t w = (uint_t)f2bf(a.x*NORMALIZER) | ((uint_t)f2bf(a.y*NORMALIZER)<<16);
      *(uint_t*)(qs + row*72 + half*32 + i*2) = w;
    }
    ss += __shfl_xor(ss, 1);
    if (half==0) diags[row] = ss*DIAGF;
  }
  __syncthreads();

  const int l = t&63, wv = t>>6;
  const int wr0 = wv*32;
  float dv[2][4];
  #pragma unroll
  for (int rt=0;rt<2;++rt)
    #pragma unroll
    for (int r=0;r<4;++r) dv[rt][r] = diags[wr0 + rt*16 + ((l>>4)<<2) + r];

  const size_t growb = (size_t)blk*128;

  if (isq){
    // ---- q side: pass1 MFMA dash -> s' bf16-packed in regs; pass2 exp+store ----
    float rmax[2][4];
    #pragma unroll
    for (int rt=0;rt<2;++rt){ rmax[rt][0]=-3e38f; rmax[rt][1]=-3e38f; rmax[rt][2]=-3e38f; rmax[rt][3]=-3e38f; }
    uint_t spu[17][2][2];
    #pragma unroll
    for (int mt=0; mt<17; ++mt){
      bf16x8 b0 = frag_ld(pjs, 72, mt*16, 0);
      bf16x8 b1 = frag_ld(pjs, 72, mt*16, 32);
      const bool valid = (mt*16 + (l&15)) < MM;
      #pragma unroll
      for (int rt=0;rt<2;++rt){
        bf16x8 a0 = frag_ld(qs, 72, wr0+rt*16, 0);
        bf16x8 a1 = frag_ld(qs, 72, wr0+rt*16, 32);
        f32x4 acc = {0.f,0.f,0.f,0.f};
        acc = mfma16(a0, b0, acc);
        acc = mfma16(a1, b1, acc);
        float sp0 = acc[0]-dv[rt][0]+SBIAS, sp1 = acc[1]-dv[rt][1]+SBIAS;
        float sp2 = acc[2]-dv[rt][2]+SBIAS, sp3 = acc[3]-dv[rt][3]+SBIAS;
        if (valid){
          rmax[rt][0] = fmaxf(rmax[rt][0], sp0); rmax[rt][1] = fmaxf(rmax[rt][1], sp1);
          rmax[rt][2] = fmaxf(rmax[rt][2], sp2); rmax[rt][3] = fmaxf(rmax[rt][3], sp3);
        }
        spu[mt][rt][0] = (uint_t)f2bf(sp0) | ((uint_t)f2bf(sp1)<<16);
        spu[mt][rt][1] = (uint_t)f2bf(sp2) | ((uint_t)f2bf(sp3)<<16);
      }
    }
    float sub[2][4];
    #pragma unroll
    for (int rt=0;rt<2;++rt){
      #pragma unroll
      for (int r=0;r<4;++r){
        float m = rmax[rt][r];
        m = fmaxf(m, __shfl_xor(m,1)); m = fmaxf(m, __shfl_xor(m,2));
        m = fmaxf(m, __shfl_xor(m,4)); m = fmaxf(m, __shfl_xor(m,8));
        // sub = max(s') + diag; the +diag is REQUIRED (R6 failure: eps does not cancel)
        sub[rt][r] = m + dv[rt][r];
      }
    }
    #pragma unroll
    for (int mt=0; mt<17; ++mt){
      const int m = mt*16 + (l&15);
      if (m < MM){
        #pragma unroll
        for (int rt=0;rt<2;++rt){
          float a0,a1,a2,a3;
          unpack2(spu[mt][rt][0], a0, a1);
          unpack2(spu[mt][rt][1], a2, a3);
          const size_t rb = growb + wr0 + rt*16 + ((l>>4)<<2);
          qp[(rb+0)*MM + m] = f2bf(RATIO*(__expf(a0 - sub[rt][0]) + KEPS));
          qp[(rb+1)*MM + m] = f2bf(RATIO*(__expf(a1 - sub[rt][1]) + KEPS));
          qp[(rb+2)*MM + m] = f2bf(RATIO*(__expf(a2 - sub[rt][2]) + KEPS));
          qp[(rb+3)*MM + m] = f2bf(RATIO*(__expf(a3 - sub[rt][3]) + KEPS));
        }
      }
    }
  } else {
    // ---- k side: s' stored bf16; block max -> device atomicMax(gmax) ----
    float rmax[2][4];
    #pragma unroll
    for (int rt=0;rt<2;++rt){ rmax[rt][0]=-3e38f; rmax[rt][1]=-3e38f; rmax[rt][2]=-3e38f; rmax[rt][3]=-3e38f; }
    for (int mt=0; mt<17; ++mt){
      bf16x8 b0 = frag_ld(pjs, 72, mt*16, 0);
      bf16x8 b1 = frag_ld(pjs, 72, mt*16, 32);
      const int m = mt*16 + (l&15);
      const bool valid = (m < MM);
      #pragma unroll
      for (int rt=0;rt<2;++rt){
        bf16x8 a0 = frag_ld(qs, 72, wr0+rt*16, 0);
        bf16x8 a1 = frag_ld(qs, 72, wr0+rt*16, 32);
        f32x4 acc = {0.f,0.f,0.f,0.f};
        acc = mfma16(a0, b0, acc);
        acc = mfma16(a1, b1, acc);
        #pragma unroll
        for (int r=0;r<4;++r){
          float sp = acc[r] - dv[rt][r] + SBIAS;
          if (valid){
            rmax[rt][r] = fmaxf(rmax[rt][r], sp);
            kd[(growb + wr0 + rt*16 + ((l>>4)<<2) + r)*MM + m] = f2bf(sp);
          }
        }
      }
    }
    float bm = -3e38f;
    #pragma unroll
    for (int rt=0;rt<2;++rt){
      #pragma unroll
      for (int r=0;r<4;++r){
        float m = rmax[rt][r];
        m = fmaxf(m, __shfl_xor(m,1)); m = fmaxf(m, __shfl_xor(m,2));
        m = fmaxf(m, __shfl_xor(m,4)); m = fmaxf(m, __shfl_xor(m,8));
        bm = fmaxf(bm, m + dv[rt][r]);
      }
    }
    bm = fmaxf(bm, __shfl_xor(bm,16));
    bm = fmaxf(bm, __shfl_xor(bm,32));
    if (l==0) smax[wv] = bm;
    __syncthreads();
    if (t==0){
      float g = fmaxf(fmaxf(smax[0],smax[1]), fmaxf(smax[2],smax[3]));
      atomicMax(gmaxu, fenc(g));
    }
  }
}

// ---------------- chunk sums via MFMA; b32 colsum + pair-packed vT staging ----------------

__global__ __launch_bounds__(256) void k_chunksum5(const ushort_t* __restrict__ kd,
                                                   const float* __restrict__ v,
                                                   const uint_t* __restrict__ gmaxu,
                                                   ushort_t* __restrict__ ctx,
                                                   float* __restrict__ z){
  __shared__ __align__(16) ushort_t kpT[272*34];  // [m][row-subtile 32]
  __shared__ __align__(16) ushort_t vT[64*136];   // [e][row 128]
  const int blk = blockIdx.x, bh = blk>>5, ch = blk&31;
  const int t = threadIdx.x, l = t&63, wv = t>>6;
  const int row0 = ch*CCH;
  const ushort_t* kg = kd + (size_t)(bh*NSEQ + row0)*MM;
  const float*    vg = v  + (size_t)(bh*NSEQ + row0)*DD;
  const float g = fdec(gmaxu[0]);

  // stage V transposed: row-pairs packed as uints
  {
    const int e = t&63, rp = t>>6;
    float rv[32];
    #pragma unroll
    for (int i=0;i<16;++i){
      rv[2*i]   = vg[(size_t)(2*(rp+4*i)  )*DD + e];
      rv[2*i+1] = vg[(size_t)(2*(rp+4*i)+1)*DD + e];
    }
    #pragma unroll
    for (int i=0;i<16;++i)
      *(uint_t*)(vT + e*136 + 2*(rp+4*i)) =
        (uint_t)f2bf(rv[2*i]) | ((uint_t)f2bf(rv[2*i+1])<<16);
  }
  // zero-fill pad m-rows 266..271 once
  for (int idx=t; idx<6*34; idx+=256) kpT[266*34 + idx] = 0;

  const int rloc  = t>>3;
  const int mlane = t&7;
  const bool hastail = (mlane < 5);
  uint_t rw[17];

#define CLOAD(KS) do{ \
    const ushort_t* src_ = kg + (size_t)((KS)*32 + rloc)*MM; \
    _Pragma("unroll") \
    for (int j=0;j<16;++j) rw[j] = *(const uint_t*)(src_ + 2*(j*8 + mlane)); \
    rw[16] = hastail ? *(const uint_t*)(src_ + 2*(128 + mlane)) : 0u; \
  }while(0)

#define CSTORE() do{ \
    _Pragma("unroll") \
    for (int j=0;j<16;++j){ \
      float a_, b_; unpack2(rw[j], a_, b_); \
      const int m_ = 2*(j*8 + mlane); \
      kpT[(m_  )*34 + rloc] = f2bf(RATIO*(__expf(a_ - g) + KEPS)); \
      kpT[(m_+1)*34 + rloc] = f2bf(RATIO*(__expf(b_ - g) + KEPS)); \
    } \
    if (hastail){ \
      float a_, b_; unpack2(rw[16], a_, b_); \
      const int m_ = 2*(128 + mlane); \
      kpT[(m_  )*34 + rloc] = f2bf(RATIO*(__expf(a_ - g) + KEPS)); \
      kpT[(m_+1)*34 + rloc] = f2bf(RATIO*(__expf(b_ - g) + KEPS)); \
    } \
  }while(0)

  f32x4 acc[17];
  #pragma unroll
  for (int i=0;i<17;++i) acc[i] = (f32x4){0.f,0.f,0.f,0.f};
  float zacc = 0.f, zacc2 = 0.f;
  const bool hasz2 = (256 + t) < MM;

  CLOAD(0);
  for (int ks=0; ks<4; ++ks){
    __syncthreads();
    CSTORE();
    __syncthreads();
    if (ks < 3) CLOAD(ks+1);

    {
      float s1 = 0.f;
      #pragma unroll
      for (int j=0;j<16;++j){
        float a_, b_; unpack2(*(const uint_t*)(kpT + t*34 + 2*j), a_, b_);
        s1 += a_; s1 += b_;
      }
      zacc += s1;
      if (t < 16){
        float s2 = 0.f;
        #pragma unroll
        for (int j=0;j<16;++j){
          float a_, b_; unpack2(*(const uint_t*)(kpT + (256+t)*34 + 2*j), a_, b_);
          s2 += a_; s2 += b_;
        }
        zacc2 += s2;
      }
    }
    bf16x8 bv = frag_ld(vT, 136, wv*16, ks*32);
    #pragma unroll
    for (int mt=0; mt<17; ++mt){
      bf16x8 a = frag_ld(kpT, 34, mt*16, 0);
      acc[mt] = mfma16(a, bv, acc[mt]);
    }
  }

  ushort_t* cg = ctx + (size_t)blk*MM*DD;
  const int e = wv*16 + (l&15);
  #pragma unroll
  for (int mt=0; mt<17; ++mt){
    #pragma unroll
    for (int r=0;r<4;++r){
      int m = mt*16 + ((l>>4)<<2) + r;
      if (m < MM) cg[(size_t)m*DD + e] = f2bf(acc[mt][r]);
    }
  }
  float* zgo = z + (size_t)blk*MM;
  zgo[t] = zacc;
  if (hasz2) zgo[256+t] = zacc2;
#undef CLOAD
#undef CSTORE
}

// ---------------- fused exclusive prefixes (ctx bf16 + z f32) ----------------

__global__ __launch_bounds__(256) void k_prefix3(ushort_t* __restrict__ ctx,
                                                 float* __restrict__ z){
  int bid = blockIdx.x;
  if (bid < NBH*67){
    int bh = bid/67, mg = bid%67;
    int t = threadIdx.x; int mo = t>>6, e = t&63;
    int m = mg*4 + mo;
    if (m >= MM) return;
    size_t base = (size_t)bh*NCH*MM*DD + (size_t)m*DD + e;
    float vals[32];
    #pragma unroll
    for (int c=0;c<NCH;++c) vals[c] = bf2f(ctx[base + (size_t)c*MM*DD]);
    float run = 0.f;
    #pragma unroll
    for (int c=0;c<NCH;++c){
      float cur = vals[c];
      ctx[base + (size_t)c*MM*DD] = f2bf(run);
      run += cur;
    }
  } else {
    int bh = bid - NBH*67, t = threadIdx.x;
    size_t base = (size_t)bh*NCH*MM;
    {
      float va[32];
      #pragma unroll
      for (int c=0;c<NCH;++c) va[c] = z[base + (size_t)c*MM + t];
      float run = 0.f;
      #pragma unroll
      for (int c=0;c<NCH;++c){ float cur = va[c]; z[base + (size_t)c*MM + t] = run; run += cur; }
    }
    if (256 + t < MM){
      float vb[32];
      #pragma unroll
      for (int c=0;c<NCH;++c) vb[c] = z[base + (size_t)c*MM + 256 + t];
      float run = 0.f;
      #pragma unroll
      for (int c=0;c<NCH;++c){ float cur = vb[c]; z[base + (size_t)c*MM + 256 + t] = run; run += cur; }
    }
  }
}

// ---------------- per-chunk output: 512 threads, z as 5th ctx e-tile (R8-verified) ----------------

__global__ __launch_bounds__(512) void k_output10(const ushort_t* __restrict__ qp,
                                                  const ushort_t* __restrict__ kd,
                                                  const float* __restrict__ v,
                                                  const ushort_t* __restrict__ ctx,
                                                  const float* __restrict__ z,
                                                  const uint_t* __restrict__ gmaxu,
                                                  float* __restrict__ out){
  __shared__ __align__(16) char lds[52224];
  ushort_t* qs   = (ushort_t*)lds;            // [128][72]  18,432 B
  ushort_t* kss  = (ushort_t*)(lds + 18432);  // [128][72]  18,432 B
  ushort_t* Ps   = (ushort_t*)lds;            // [128][136] 34,816 B (aliases qs+kss)
  ushort_t* ctxT = (ushort_t*)(lds + 36864);  // [80][72]   11,520 B (e-major; e=64 is z, 65..79 zero)
  ushort_t* vT   = (ushort_t*)(lds + 34816);  // [64][136]  17,408 B (after Ps end; post m-loop)

  const int blk = blockIdx.x, bh = blk>>5, ch = blk&31;
  const int t = threadIdx.x, l = t&63, wv = t>>6;   // wv in 0..7
  const int row0 = ch*CCH;
  const int wr0 = wv*16;                            // wave owns rows wr0..wr0+15
  const float g = fdec(gmaxu[0]);

  const ushort_t* qg = qp + (size_t)(bh*NSEQ + row0)*MM;
  const ushort_t* kg = kd + (size_t)(bh*NSEQ + row0)*MM;
  const float*    vg = v  + (size_t)(bh*NSEQ + row0)*DD;
  const ushort_t* ctxg = ctx + (size_t)blk*MM*DD;
  const float*    zg = z  + (size_t)blk*MM;

  // register prefetch state
  const int mcol  = (t&31)<<1;   // q/k: m-offset within 64-tile (uint granularity)
  const int qrow0 = t>>5;        // q/k: rows qrow0 + 16i (qrow0 in 0..15)
  const int ce    = t&63;        // ctx: e
  const int cm0   = t>>6;        // ctx: mm = cm0 + 8i (cm0 in 0..7)
  uint_t rq[8], rk[8];
  ushort_t rc[8];
  float rz;

#define LOADREGS(MT) do{ \
    const int m0_ = (MT)*64; \
    const bool vq_ = (m0_ + mcol) < MM; \
    _Pragma("unroll") \
    for (int i=0;i<8;++i){ \
      int row_ = qrow0 + 16*i; \
      rq[i] = vq_ ? *(const uint_t*)(qg + (size_t)row_*MM + m0_ + mcol) : 0u; \
      rk[i] = vq_ ? *(const uint_t*)(kg + (size_t)row_*MM + m0_ + mcol) : 0u; \
    } \
    _Pragma("unroll") \
    for (int i=0;i<8;++i){ \
      int mm_ = cm0 + 8*i; \
      rc[i] = (m0_ + mm_ < MM) ? ctxg[(size_t)(m0_ + mm_)*DD + ce] : (ushort_t)0; \
    } \
    rz = (m0_ + (t&63) < MM) ? zg[m0_ + (t&63)] : 0.f; \
  }while(0)

#define WRITELDS(MT) do{ \
    const int m0_ = (MT)*64; \
    const bool vq_ = (m0_ + mcol) < MM; \
    _Pragma("unroll") \
    for (int i=0;i<8;++i){ \
      int row_ = qrow0 + 16*i; \
      *(uint_t*)(qs + row_*72 + mcol) = rq[i]; \
      uint_t ko_ = 0u; \
      if (vq_){ \
        float a_, b_; unpack2(rk[i], a_, b_); \
        a_ = RATIO*(__expf(a_ - g) + KEPS); \
        b_ = RATIO*(__expf(b_ - g) + KEPS); \
        ko_ = (uint_t)f2bf(a_) | ((uint_t)f2bf(b_)<<16); \
      } \
      *(uint_t*)(kss + row_*72 + mcol) = ko_; \
    } \
    _Pragma("unroll") \
    for (int i=0;i<8;++i) ctxT[ce*72 + cm0 + 8*i] = rc[i]; \
    if (t < 64) ctxT[64*72 + t] = f2bf(rz); \
  }while(0)

  // zero the ctxT pad e-rows 65..79 once (never rewritten)
  for (int idx=t; idx<15*72; idx+=512) ctxT[65*72 + idx] = 0;

  f32x4 acc[8];
  f32x4 oacc[5];
  #pragma unroll
  for (int ct=0;ct<8;++ct) acc[ct] = (f32x4){0.f,0.f,0.f,0.f};
  #pragma unroll
  for (int et=0;et<5;++et) oacc[et] = (f32x4){0.f,0.f,0.f,0.f};

  LOADREGS(0);
  for (int mt=0; mt<5; ++mt){
    __syncthreads();                  // readers of previous tile done (pad-zero visible at mt=0)
    WRITELDS(mt);
    __syncthreads();
    if (mt < 4) LOADREGS(mt+1);       // overlaps MFMA below

    bf16x8 aq[2];
    aq[0] = frag_ld(qs, 72, wr0, 0);
    aq[1] = frag_ld(qs, 72, wr0, 32);
    #pragma unroll
    for (int ct=0;ct<8;++ct){
      bf16x8 b0 = frag_ld(kss, 72, ct*16, 0);
      bf16x8 b1 = frag_ld(kss, 72, ct*16, 32);
      acc[ct] = mfma16(aq[0], b0, acc[ct]);
      acc[ct] = mfma16(aq[1], b1, acc[ct]);
    }
    #pragma unroll
    for (int et=0;et<5;++et){
      bf16x8 b0 = frag_ld(ctxT, 72, et*16, 0);
      bf16x8 b1 = frag_ld(ctxT, 72, et*16, 32);
      oacc[et] = mfma16(aq[0], b0, oacc[et]);
      oacc[et] = mfma16(aq[1], b1, oacc[et]);
    }
  }
  __syncthreads();  // all MFMA readers done before Ps/vT overwrite qs/kss/ctxT

  // issue V loads early (row-pairs; latency hides under mask/pack VALU below)
  float rv[16];
  const int rp = t>>6;   // == wv, 0..7; pair index rp+8i
  {
    #pragma unroll
    for (int i=0;i<8;++i){
      rv[2*i]   = vg[(size_t)(2*(rp+8*i)  )*DD + ce];
      rv[2*i+1] = vg[(size_t)(2*(rp+8*i)+1)*DD + ce];
    }
  }

  // ---- mask + row-sum + write P (bf16) to LDS ----
  float ds[4] = {0.f,0.f,0.f,0.f};
  #pragma unroll
  for (int ct=0;ct<8;++ct){
    #pragma unroll
    for (int r=0;r<4;++r){
      int i = wr0 + ((l>>4)<<2) + r;
      int j = ct*16 + (l&15);
      float m = (j <= i) ? acc[ct][r] : 0.f;
      acc[ct][r] = m;
      ds[r] += m;
    }
  }
  #pragma unroll
  for (int ct=0;ct<8;++ct){
    #pragma unroll
    for (int r=0;r<4;++r){
      int i = wr0 + ((l>>4)<<2) + r;
      Ps[i*136 + ct*16 + (l&15)] = f2bf(acc[ct][r]);
    }
  }
  // full D per lane: masked-S rowsum + z-dot from MFMA e-column 64 (lane l&48 holds col 0)
  float dtot[4];
  #pragma unroll
  for (int r=0;r<4;++r){
    float d = ds[r];
    d += __shfl_xor(d,1); d += __shfl_xor(d,2); d += __shfl_xor(d,4); d += __shfl_xor(d,8);
    dtot[r] = d + __shfl(oacc[4][r], l & 48);
  }
  // write V (transposed bf16, pair-packed uints) into region after Ps
  {
    #pragma unroll
    for (int i=0;i<8;++i)
      *(uint_t*)(vT + ce*136 + 2*(rp+8*i)) =
        (uint_t)f2bf(rv[2*i]) | ((uint_t)f2bf(rv[2*i+1])<<16);
  }
  __syncthreads();

  // ---- PV: oacc += P V ----
  #pragma unroll
  for (int kt=0;kt<4;++kt){
    bf16x8 ap = frag_ld(Ps, 136, wr0, kt*32);
    #pragma unroll
    for (int et=0;et<4;++et){
      bf16x8 bv = frag_ld(vT, 136, et*16, kt*32);
      oacc[et] = mfma16(ap, bv, oacc[et]);
    }
  }

  // ---- epilogue ----
  float* og = out + (size_t)(bh*NSEQ + row0)*DD;
  #pragma unroll
  for (int r=0;r<4;++r){
    int i = wr0 + ((l>>4)<<2) + r;
    float dinv = 1.0f / dtot[r];
    #pragma unroll
    for (int et=0;et<4;++et)
      og[(size_t)i*DD + et*16 + (l&15)] = oacc[et][r] * dinv;
  }
#undef LOADREGS
#undef WRITELDS
}

// ---------------- launch ----------------

extern "C" void kernel_launch(void* const* d_in, const int* in_sizes, int n_in,
                              void* d_out, int out_size, void* d_ws, size_t ws_size,
                              hipStream_t stream) {
  const float* q    = (const float*)d_in[0];
  const float* k    = (const float*)d_in[1];
  const float* v    = (const float*)d_in[2];
  const float* proj = (const float*)d_in[3];
  float* out = (float*)d_out;
  char* ws = (char*)d_ws;

  const size_t QP_OFF   = 0;             // bf16 [rows][266]  final qp
  const size_t KD_OFF   = 69730304ull;   // bf16 [rows][266]  s'_k (pre-exp)
  const size_t CTX_OFF  = 139460608ull;  // bf16 [1024][266][64] = 34,865,152
  const size_t Z_OFF    = 174325760ull;  // f32  [1024][266] = 1,089,536
  const size_t GMAX_OFF = 175415296ull;  // uint [1] (monotonic-encoded float max)
  if (ws_size < 175416000ull) return;

  ushort_t* qp   = (ushort_t*)(ws + QP_OFF);
  ushort_t* kd   = (ushort_t*)(ws + KD_OFF);
  ushort_t* ctx  = (ushort_t*)(ws + CTX_OFF);
  float* z       = (float*)(ws + Z_OFF);
  uint_t* gmaxu  = (uint_t*)(ws + GMAX_OFF);

  hipMemsetAsync(gmaxu, 0, 4, stream);   // encoded floor for atomicMax
  k_dash_both<<<2*(NROWS/128), 256, 0, stream>>>(q, k, proj, qp, kd, gmaxu);
  k_chunksum5<<<NBH*NCH, 256, 0, stream>>>(kd, v, gmaxu, ctx, z);
  k_prefix3  <<<NBH*67 + NBH, 256, 0, stream>>>(ctx, z);
  k_output10 <<<NBH*NCH, 512, 0, stream>>>(qp, kd, v, ctx, z, gmaxu, out);
}

// Round 19
// 198.603 us; speedup vs baseline: 1.3103x; 1.0013x over previous
//
#include <hip/hip_runtime.h>

#define BB 4
#define HH 8
#define NSEQ 4096
#define DD 64
#define MM 266
#define CCH 128
#define NCH 32
#define NBH (BB*HH)
#define NROWS (NBH*NSEQ)

#define NORMALIZER 0.35355339059327373f
#define DIAGF 0.0625f
#define RATIO 0.0613140017f
#define KEPS 1e-4f
#define SBIAS 4.0f

typedef unsigned short ushort_t;
typedef unsigned int uint_t;

typedef __attribute__((ext_vector_type(8))) short bf16x8;
typedef __attribute__((ext_vector_type(4))) float f32x4;

__device__ __forceinline__ f32x4 mfma16(bf16x8 a, bf16x8 b, f32x4 c){
  return __builtin_amdgcn_mfma_f32_16x16x32_bf16(a, b, c, 0, 0, 0);
}

__device__ __forceinline__ ushort_t f2bf(float x){
  union { float f; uint_t u; } v; v.f = x;
  uint_t r = (v.u + 0x7FFFu + ((v.u >> 16) & 1u)) >> 16;
  return (ushort_t)r;
}
__device__ __forceinline__ float bf2f(ushort_t h){
  union { uint_t u; float f; } v; v.u = ((uint_t)h) << 16;
  return v.f;
}
__device__ __forceinline__ void unpack2(uint_t w, float& lo, float& hi){
  union { uint_t u; float f; } a, b;
  a.u = w << 16; b.u = w & 0xFFFF0000u;
  lo = a.f; hi = b.f;
}

// monotonic float<->uint for atomicMax-based global max (cell memset to 0 = floor)
__device__ __forceinline__ uint_t fenc(float f){
  uint_t b = __float_as_uint(f);
  return (b & 0x80000000u) ? ~b : (b | 0x80000000u);
}
__device__ __forceinline__ float fdec(uint_t u){
  uint_t b = (u >> 31) ? (u ^ 0x80000000u) : ~u;
  return __uint_as_float(b);
}

// MFMA fragment load from a row-major LDS tile.
// lane l supplies element [spatial = s0 + (l&15)][k = koff + (l>>4)*8 + j], j=0..7
// NOTE (R14 lesson): strides whose byte size is not 0 mod 16 split every ds_*_b128
// and cost ~2x. 72 and 136 ushorts are the verified-aligned choices.
__device__ __forceinline__ bf16x8 frag_ld(const ushort_t* tile, int stride, int s0, int koff){
  const int l = threadIdx.x & 63;
  return *(const bf16x8*)(tile + (s0 + (l&15))*stride + koff + ((l>>4)<<3));
}

// ---------------- fused dash kernel: blocks [0,1024) = q side, [1024,2048) = k side ----------------

__global__ __launch_bounds__(256) void k_dash_both(const float* __restrict__ q,
                                                   const float* __restrict__ k,
                                                   const float* __restrict__ proj,
                                                   ushort_t* __restrict__ qp,
                                                   ushort_t* __restrict__ kd,
                                                   uint_t* __restrict__ gmaxu){
  __shared__ __align__(16) ushort_t pjs[272*72];
  __shared__ __align__(16) ushort_t qs[128*72];
  __shared__ float diags[128];
  __shared__ float smax[4];
  const int t = threadIdx.x;
  const bool isq = blockIdx.x < (NROWS/128);
  const int blk = isq ? blockIdx.x : (blockIdx.x - NROWS/128);
  const float* x = isq ? q : k;

  #pragma unroll
  for (int h=0; h<2; ++h){
    float2 pv[17];
    #pragma unroll
    for (int i=0;i<17;++i){
      int idx = t + (h*17+i)*256;
      int m = idx>>5, dp = (idx&31)*2;
      float2 p2 = {0.f,0.f};
      if (m < MM) p2 = *(const float2*)(proj + (size_t)m*DD + dp);
      pv[i] = p2;
    }
    #pragma unroll
    for (int i=0;i<17;++i){
      int idx = t + (h*17+i)*256;
      int m = idx>>5, dp = (idx&31)*2;
      *(uint_t*)(pjs + m*72 + dp) = (uint_t)f2bf(pv[i].x) | ((uint_t)f2bf(pv[i].y)<<16);
    }
  }
  {
    const int row = t>>1, half = t&1;
    const float2* xr = (const float2*)(x + ((size_t)blk*128 + row)*DD + half*32);
    float ss = 0.f;
    #pragma unroll
    for (int i=0;i<16;++i){
      float2 a = xr[i];
      ss += a.x*a.x + a.y*a.y;
      uint_t w = (uint_t)f2bf(a.x*NORMALIZER) | ((uint_t)f2bf(a.y*NORMALIZER)<<16);
      *(uint_t*)(qs + row*72 + half*32 + i*2) = w;
    }
    ss += __shfl_xor(ss, 1);
    if (half==0) diags[row] = ss*DIAGF;
  }
  __syncthreads();

  const int l = t&63, wv = t>>6;
  const int wr0 = wv*32;
  float dv[2][4];
  #pragma unroll
  for (int rt=0;rt<2;++rt)
    #pragma unroll
    for (int r=0;r<4;++r) dv[rt][r] = diags[wr0 + rt*16 + ((l>>4)<<2) + r];

  const size_t growb = (size_t)blk*128;

  if (isq){
    float rmax[2][4];
    #pragma unroll
    for (int rt=0;rt<2;++rt){ rmax[rt][0]=-3e38f; rmax[rt][1]=-3e38f; rmax[rt][2]=-3e38f; rmax[rt][3]=-3e38f; }
    uint_t spu[17][2][2];
    #pragma unroll
    for (int mt=0; mt<17; ++mt){
      bf16x8 b0 = frag_ld(pjs, 72, mt*16, 0);
      bf16x8 b1 = frag_ld(pjs, 72, mt*16, 32);
      const bool valid = (mt*16 + (l&15)) < MM;
      #pragma unroll
      for (int rt=0;rt<2;++rt){
        bf16x8 a0 = frag_ld(qs, 72, wr0+rt*16, 0);
        bf16x8 a1 = frag_ld(qs, 72, wr0+rt*16, 32);
        f32x4 acc = {0.f,0.f,0.f,0.f};
        acc = mfma16(a0, b0, acc);
        acc = mfma16(a1, b1, acc);
        float sp0 = acc[0]-dv[rt][0]+SBIAS, sp1 = acc[1]-dv[rt][1]+SBIAS;
        float sp2 = acc[2]-dv[rt][2]+SBIAS, sp3 = acc[3]-dv[rt][3]+SBIAS;
        if (valid){
          rmax[rt][0] = fmaxf(rmax[rt][0], sp0); rmax[rt][1] = fmaxf(rmax[rt][1], sp1);
          rmax[rt][2] = fmaxf(rmax[rt][2], sp2); rmax[rt][3] = fmaxf(rmax[rt][3], sp3);
        }
        spu[mt][rt][0] = (uint_t)f2bf(sp0) | ((uint_t)f2bf(sp1)<<16);
        spu[mt][rt][1] = (uint_t)f2bf(sp2) | ((uint_t)f2bf(sp3)<<16);
      }
    }
    float sub[2][4];
    #pragma unroll
    for (int rt=0;rt<2;++rt){
      #pragma unroll
      for (int r=0;r<4;++r){
        float m = rmax[rt][r];
        m = fmaxf(m, __shfl_xor(m,1)); m = fmaxf(m, __shfl_xor(m,2));
        m = fmaxf(m, __shfl_xor(m,4)); m = fmaxf(m, __shfl_xor(m,8));
        // sub = max(s') + diag; the +diag is REQUIRED (R6 failure: eps does not cancel)
        sub[rt][r] = m + dv[rt][r];
      }
    }
    #pragma unroll
    for (int mt=0; mt<17; ++mt){
      const int m = mt*16 + (l&15);
      if (m < MM){
        #pragma unroll
        for (int rt=0;rt<2;++rt){
          float a0,a1,a2,a3;
          unpack2(spu[mt][rt][0], a0, a1);
          unpack2(spu[mt][rt][1], a2, a3);
          const size_t rb = growb + wr0 + rt*16 + ((l>>4)<<2);
          qp[(rb+0)*MM + m] = f2bf(RATIO*(__expf(a0 - sub[rt][0]) + KEPS));
          qp[(rb+1)*MM + m] = f2bf(RATIO*(__expf(a1 - sub[rt][1]) + KEPS));
          qp[(rb+2)*MM + m] = f2bf(RATIO*(__expf(a2 - sub[rt][2]) + KEPS));
          qp[(rb+3)*MM + m] = f2bf(RATIO*(__expf(a3 - sub[rt][3]) + KEPS));
        }
      }
    }
  } else {
    float rmax[2][4];
    #pragma unroll
    for (int rt=0;rt<2;++rt){ rmax[rt][0]=-3e38f; rmax[rt][1]=-3e38f; rmax[rt][2]=-3e38f; rmax[rt][3]=-3e38f; }
    for (int mt=0; mt<17; ++mt){
      bf16x8 b0 = frag_ld(pjs, 72, mt*16, 0);
      bf16x8 b1 = frag_ld(pjs, 72, mt*16, 32);
      const int m = mt*16 + (l&15);
      const bool valid = (m < MM);
      #pragma unroll
      for (int rt=0;rt<2;++rt){
        bf16x8 a0 = frag_ld(qs, 72, wr0+rt*16, 0);
        bf16x8 a1 = frag_ld(qs, 72, wr0+rt*16, 32);
        f32x4 acc = {0.f,0.f,0.f,0.f};
        acc = mfma16(a0, b0, acc);
        acc = mfma16(a1, b1, acc);
        #pragma unroll
        for (int r=0;r<4;++r){
          float sp = acc[r] - dv[rt][r] + SBIAS;
          if (valid){
            rmax[rt][r] = fmaxf(rmax[rt][r], sp);
            kd[(growb + wr0 + rt*16 + ((l>>4)<<2) + r)*MM + m] = f2bf(sp);
          }
        }
      }
    }
    float bm = -3e38f;
    #pragma unroll
    for (int rt=0;rt<2;++rt){
      #pragma unroll
      for (int r=0;r<4;++r){
        float m = rmax[rt][r];
        m = fmaxf(m, __shfl_xor(m,1)); m = fmaxf(m, __shfl_xor(m,2));
        m = fmaxf(m, __shfl_xor(m,4)); m = fmaxf(m, __shfl_xor(m,8));
        bm = fmaxf(bm, m + dv[rt][r]);
      }
    }
    bm = fmaxf(bm, __shfl_xor(bm,16));
    bm = fmaxf(bm, __shfl_xor(bm,32));
    if (l==0) smax[wv] = bm;
    __syncthreads();
    if (t==0){
      float g = fmaxf(fmaxf(smax[0],smax[1]), fmaxf(smax[2],smax[3]));
      atomicMax(gmaxu, fenc(g));
    }
  }
}

// ---------------- chunk sums via MFMA; exp hoisted out of barrier window ----------------

__global__ __launch_bounds__(256) void k_chunksum8(const ushort_t* __restrict__ kd,
                                                   const float* __restrict__ v,
                                                   const uint_t* __restrict__ gmaxu,
                                                   ushort_t* __restrict__ ctx,
                                                   float* __restrict__ z){
  __shared__ __align__(16) ushort_t kpT[272*34];  // [m][row-subtile 32]
  __shared__ __align__(16) ushort_t vT[64*136];   // [e][row 128]
  const int blk = blockIdx.x, bh = blk>>5, ch = blk&31;
  const int t = threadIdx.x, l = t&63, wv = t>>6;
  const int row0 = ch*CCH;
  const ushort_t* kg = kd + (size_t)(bh*NSEQ + row0)*MM;
  const float*    vg = v  + (size_t)(bh*NSEQ + row0)*DD;
  const float g = fdec(gmaxu[0]);

  // stage V transposed: row-pairs packed as uints
  {
    const int e = t&63, rp = t>>6;
    float rv[32];
    #pragma unroll
    for (int i=0;i<16;++i){
      rv[2*i]   = vg[(size_t)(2*(rp+4*i)  )*DD + e];
      rv[2*i+1] = vg[(size_t)(2*(rp+4*i)+1)*DD + e];
    }
    #pragma unroll
    for (int i=0;i<16;++i)
      *(uint_t*)(vT + e*136 + 2*(rp+4*i)) =
        (uint_t)f2bf(rv[2*i]) | ((uint_t)f2bf(rv[2*i+1])<<16);
  }
  for (int idx=t; idx<6*34; idx+=256) kpT[266*34 + idx] = 0;

  const int rloc  = t>>3;
  const int mlane = t&7;
  const bool hastail = (mlane < 5);
  uint_t rw[17];   // raw after CLOAD; exp'd packed bf16 pair after EXPPACK

#define CLOAD(KS) do{ \
    const ushort_t* src_ = kg + (size_t)((KS)*32 + rloc)*MM; \
    _Pragma("unroll") \
    for (int j=0;j<16;++j) rw[j] = *(const uint_t*)(src_ + 2*(j*8 + mlane)); \
    rw[16] = hastail ? *(const uint_t*)(src_ + 2*(128 + mlane)) : 0u; \
  }while(0)

#define EXPPACK() do{ \
    _Pragma("unroll") \
    for (int j=0;j<17;++j){ \
      if (j < 16 || hastail){ \
        float a_, b_; unpack2(rw[j], a_, b_); \
        a_ = RATIO*(__expf(a_ - g) + KEPS); \
        b_ = RATIO*(__expf(b_ - g) + KEPS); \
        rw[j] = (uint_t)f2bf(a_) | ((uint_t)f2bf(b_)<<16); \
      } \
    } \
  }while(0)

#define CSTORE() do{ \
    _Pragma("unroll") \
    for (int j=0;j<16;++j){ \
      const int m_ = 2*(j*8 + mlane); \
      kpT[(m_  )*34 + rloc] = (ushort_t)rw[j]; \
      kpT[(m_+1)*34 + rloc] = (ushort_t)(rw[j]>>16); \
    } \
    if (hastail){ \
      const int m_ = 2*(128 + mlane); \
      kpT[(m_  )*34 + rloc] = (ushort_t)rw[16]; \
      kpT[(m_+1)*34 + rloc] = (ushort_t)(rw[16]>>16); \
    } \
  }while(0)

  f32x4 acc[17];
  #pragma unroll
  for (int i=0;i<17;++i) acc[i] = (f32x4){0.f,0.f,0.f,0.f};
  float zacc = 0.f, zacc2 = 0.f;
  const bool hasz2 = (256 + t) < MM;

  CLOAD(0);
  EXPPACK();                         // prologue: waits loads, exps off critical path thereafter
  for (int ks=0; ks<4; ++ks){
    __syncthreads();
    CSTORE();                        // pure stores between barriers
    __syncthreads();
    if (ks < 3) CLOAD(ks+1);         // loads overlap colsum+MFMA

    {
      float s1 = 0.f;
      #pragma unroll
      for (int j=0;j<16;++j){
        float a_, b_; unpack2(*(const uint_t*)(kpT + t*34 + 2*j), a_, b_);
        s1 += a_; s1 += b_;
      }
      zacc += s1;
      if (t < 16){
        float s2 = 0.f;
        #pragma unroll
        for (int j=0;j<16;++j){
          float a_, b_; unpack2(*(const uint_t*)(kpT + (256+t)*34 + 2*j), a_, b_);
          s2 += a_; s2 += b_;
        }
        zacc2 += s2;
      }
    }
    bf16x8 bv = frag_ld(vT, 136, wv*16, ks*32);
    #pragma unroll
    for (int mt=0; mt<17; ++mt){
      bf16x8 a = frag_ld(kpT, 34, mt*16, 0);
      acc[mt] = mfma16(a, bv, acc[mt]);
    }
    if (ks < 3) EXPPACK();           // exp overlaps MFMA execution (separate pipes)
  }

  ushort_t* cg = ctx + (size_t)blk*MM*DD;
  const int e = wv*16 + (l&15);
  #pragma unroll
  for (int mt=0; mt<17; ++mt){
    #pragma unroll
    for (int r=0;r<4;++r){
      int m = mt*16 + ((l>>4)<<2) + r;
      if (m < MM) cg[(size_t)m*DD + e] = f2bf(acc[mt][r]);
    }
  }
  float* zgo = z + (size_t)blk*MM;
  zgo[t] = zacc;
  if (hasz2) zgo[256+t] = zacc2;
#undef CLOAD
#undef EXPPACK
#undef CSTORE
}

// ---------------- fused exclusive prefixes (ctx bf16 + z f32) ----------------

__global__ __launch_bounds__(256) void k_prefix3(ushort_t* __restrict__ ctx,
                                                 float* __restrict__ z){
  int bid = blockIdx.x;
  if (bid < NBH*67){
    int bh = bid/67, mg = bid%67;
    int t = threadIdx.x; int mo = t>>6, e = t&63;
    int m = mg*4 + mo;
    if (m >= MM) return;
    size_t base = (size_t)bh*NCH*MM*DD + (size_t)m*DD + e;
    float vals[32];
    #pragma unroll
    for (int c=0;c<NCH;++c) vals[c] = bf2f(ctx[base + (size_t)c*MM*DD]);
    float run = 0.f;
    #pragma unroll
    for (int c=0;c<NCH;++c){
      float cur = vals[c];
      ctx[base + (size_t)c*MM*DD] = f2bf(run);
      run += cur;
    }
  } else {
    int bh = bid - NBH*67, t = threadIdx.x;
    size_t base = (size_t)bh*NCH*MM;
    {
      float va[32];
      #pragma unroll
      for (int c=0;c<NCH;++c) va[c] = z[base + (size_t)c*MM + t];
      float run = 0.f;
      #pragma unroll
      for (int c=0;c<NCH;++c){ float cur = va[c]; z[base + (size_t)c*MM + t] = run; run += cur; }
    }
    if (256 + t < MM){
      float vb[32];
      #pragma unroll
      for (int c=0;c<NCH;++c) vb[c] = z[base + (size_t)c*MM + 256 + t];
      float run = 0.f;
      #pragma unroll
      for (int c=0;c<NCH;++c){ float cur = vb[c]; z[base + (size_t)c*MM + 256 + t] = run; run += cur; }
    }
  }
}

// ---------------- per-chunk output: 512 threads; kss exp hoisted out of barrier window ----------------

__global__ __launch_bounds__(512) void k_output11(const ushort_t* __restrict__ qp,
                                                  const ushort_t* __restrict__ kd,
                                                  const float* __restrict__ v,
                                                  const ushort_t* __restrict__ ctx,
                                                  const float* __restrict__ z,
                                                  const uint_t* __restrict__ gmaxu,
                                                  float* __restrict__ out){
  __shared__ __align__(16) char lds[52224];
  ushort_t* qs   = (ushort_t*)lds;            // [128][72]  18,432 B
  ushort_t* kss  = (ushort_t*)(lds + 18432);  // [128][72]  18,432 B
  ushort_t* Ps   = (ushort_t*)lds;            // [128][136] 34,816 B (aliases qs+kss)
  ushort_t* ctxT = (ushort_t*)(lds + 36864);  // [80][72]   11,520 B (e-major; e=64 is z, 65..79 zero)
  ushort_t* vT   = (ushort_t*)(lds + 34816);  // [64][136]  17,408 B (after Ps end; post m-loop)

  const int blk = blockIdx.x, bh = blk>>5, ch = blk&31;
  const int t = threadIdx.x, l = t&63, wv = t>>6;   // wv in 0..7
  const int row0 = ch*CCH;
  const int wr0 = wv*16;                            // wave owns rows wr0..wr0+15
  const float g = fdec(gmaxu[0]);

  const ushort_t* qg = qp + (size_t)(bh*NSEQ + row0)*MM;
  const ushort_t* kg = kd + (size_t)(bh*NSEQ + row0)*MM;
  const float*    vg = v  + (size_t)(bh*NSEQ + row0)*DD;
  const ushort_t* ctxg = ctx + (size_t)blk*MM*DD;
  const float*    zg = z  + (size_t)blk*MM;

  // register prefetch state
  const int mcol  = (t&31)<<1;   // q/k: m-offset within 64-tile (uint granularity)
  const int qrow0 = t>>5;        // q/k: rows qrow0 + 16i (qrow0 in 0..15)
  const int ce    = t&63;        // ctx: e
  const int cm0   = t>>6;        // ctx: mm = cm0 + 8i (cm0 in 0..7)
  uint_t rq[8], rk[8];           // rk: raw after LOADREGS, exp'd packed after EXPPACKK
  ushort_t rc[8];
  float rz;

#define LOADREGS(MT) do{ \
    const int m0_ = (MT)*64; \
    const bool vq_ = (m0_ + mcol) < MM; \
    _Pragma("unroll") \
    for (int i=0;i<8;++i){ \
      int row_ = qrow0 + 16*i; \
      rq[i] = vq_ ? *(const uint_t*)(qg + (size_t)row_*MM + m0_ + mcol) : 0u; \
      rk[i] = vq_ ? *(const uint_t*)(kg + (size_t)row_*MM + m0_ + mcol) : 0u; \
    } \
    _Pragma("unroll") \
    for (int i=0;i<8;++i){ \
      int mm_ = cm0 + 8*i; \
      rc[i] = (m0_ + mm_ < MM) ? ctxg[(size_t)(m0_ + mm_)*DD + ce] : (ushort_t)0; \
    } \
    rz = (m0_ + (t&63) < MM) ? zg[m0_ + (t&63)] : 0.f; \
  }while(0)

#define EXPPACKK(MT) do{ \
    const bool vq_ = ((MT)*64 + mcol) < MM; \
    if (vq_){ \
      _Pragma("unroll") \
      for (int i=0;i<8;++i){ \
        float a_, b_; unpack2(rk[i], a_, b_); \
        a_ = RATIO*(__expf(a_ - g) + KEPS); \
        b_ = RATIO*(__expf(b_ - g) + KEPS); \
        rk[i] = (uint_t)f2bf(a_) | ((uint_t)f2bf(b_)<<16); \
      } \
    } \
  }while(0)

#define WRITELDS() do{ \
    _Pragma("unroll") \
    for (int i=0;i<8;++i){ \
      int row_ = qrow0 + 16*i; \
      *(uint_t*)(qs + row_*72 + mcol) = rq[i]; \
      *(uint_t*)(kss + row_*72 + mcol) = rk[i]; \
    } \
    _Pragma("unroll") \
    for (int i=0;i<8;++i) ctxT[ce*72 + cm0 + 8*i] = rc[i]; \
    if (t < 64) ctxT[64*72 + t] = f2bf(rz); \
  }while(0)

  // zero the ctxT pad e-rows 65..79 once (never rewritten)
  for (int idx=t; idx<15*72; idx+=512) ctxT[65*72 + idx] = 0;

  f32x4 acc[8];
  f32x4 oacc[5];
  #pragma unroll
  for (int ct=0;ct<8;++ct) acc[ct] = (f32x4){0.f,0.f,0.f,0.f};
  #pragma unroll
  for (int et=0;et<5;++et) oacc[et] = (f32x4){0.f,0.f,0.f,0.f};

  LOADREGS(0);
  EXPPACKK(0);                       // prologue exp (waits loads; fine once)
  for (int mt=0; mt<5; ++mt){
    __syncthreads();                 // readers of previous tile done (pad-zero visible at mt=0)
    WRITELDS();                      // pure stores between barriers
    __syncthreads();
    if (mt < 4) LOADREGS(mt+1);      // loads overlap MFMA below

    bf16x8 aq[2];
    aq[0] = frag_ld(qs, 72, wr0, 0);
    aq[1] = frag_ld(qs, 72, wr0, 32);
    #pragma unroll
    for (int ct=0;ct<8;++ct){
      bf16x8 b0 = frag_ld(kss, 72, ct*16, 0);
      bf16x8 b1 = frag_ld(kss, 72, ct*16, 32);
      acc[ct] = mfma16(aq[0], b0, acc[ct]);
      acc[ct] = mfma16(aq[1], b1, acc[ct]);
    }
    #pragma unroll
    for (int et=0;et<5;++et){
      bf16x8 b0 = frag_ld(ctxT, 72, et*16, 0);
      bf16x8 b1 = frag_ld(ctxT, 72, et*16, 32);
      oacc[et] = mfma16(aq[0], b0, oacc[et]);
      oacc[et] = mfma16(aq[1], b1, oacc[et]);
    }
    if (mt < 4) EXPPACKK(mt+1);      // exp overlaps MFMA execution (separate pipes)
  }
  __syncthreads();  // all MFMA readers done before Ps/vT overwrite qs/kss/ctxT

  // issue V loads early (row-pairs; latency hides under mask/pack VALU below)
  float rv[16];
  const int rp = t>>6;   // == wv, 0..7; pair index rp+8i
  {
    #pragma unroll
    for (int i=0;i<8;++i){
      rv[2*i]   = vg[(size_t)(2*(rp+8*i)  )*DD + ce];
      rv[2*i+1] = vg[(size_t)(2*(rp+8*i)+1)*DD + ce];
    }
  }

  // ---- mask + row-sum + write P (bf16) to LDS ----
  float ds[4] = {0.f,0.f,0.f,0.f};
  #pragma unroll
  for (int ct=0;ct<8;++ct){
    #pragma unroll
    for (int r=0;r<4;++r){
      int i = wr0 + ((l>>4)<<2) + r;
      int j = ct*16 + (l&15);
      float m = (j <= i) ? acc[ct][r] : 0.f;
      acc[ct][r] = m;
      ds[r] += m;
    }
  }
  #pragma unroll
  for (int ct=0;ct<8;++ct){
    #pragma unroll
    for (int r=0;r<4;++r){
      int i = wr0 + ((l>>4)<<2) + r;
      Ps[i*136 + ct*16 + (l&15)] = f2bf(acc[ct][r]);
    }
  }
  // full D per lane: masked-S rowsum + z-dot from MFMA e-column 64 (lane l&48 holds col 0)
  float dtot[4];
  #pragma unroll
  for (int r=0;r<4;++r){
    float d = ds[r];
    d += __shfl_xor(d,1); d += __shfl_xor(d,2); d += __shfl_xor(d,4); d += __shfl_xor(d,8);
    dtot[r] = d + __shfl(oacc[4][r], l & 48);
  }
  // write V (transposed bf16, pair-packed uints) into region after Ps
  {
    #pragma unroll
    for (int i=0;i<8;++i)
      *(uint_t*)(vT + ce*136 + 2*(rp+8*i)) =
        (uint_t)f2bf(rv[2*i]) | ((uint_t)f2bf(rv[2*i+1])<<16);
  }
  __syncthreads();

  // ---- PV: oacc += P V ----
  #pragma unroll
  for (int kt=0;kt<4;++kt){
    bf16x8 ap = frag_ld(Ps, 136, wr0, kt*32);
    #pragma unroll
    for (int et=0;et<4;++et){
      bf16x8 bv = frag_ld(vT, 136, et*16, kt*32);
      oacc[et] = mfma16(ap, bv, oacc[et]);
    }
  }

  // ---- epilogue ----
  float* og = out + (size_t)(bh*NSEQ + row0)*DD;
  #pragma unroll
  for (int r=0;r<4;++r){
    int i = wr0 + ((l>>4)<<2) + r;
    float dinv = 1.0f / dtot[r];
    #pragma unroll
    for (int et=0;et<4;++et)
      og[(size_t)i*DD + et*16 + (l&15)] = oacc[et][r] * dinv;
  }
#undef LOADREGS
#undef EXPPACKK
#undef WRITELDS
}

// ---------------- launch ----------------

extern "C" void kernel_launch(void* const* d_in, const int* in_sizes, int n_in,
                              void* d_out, int out_size, void* d_ws, size_t ws_size,
                              hipStream_t stream) {
  const float* q    = (const float*)d_in[0];
  const float* k    = (const float*)d_in[1];
  const float* v    = (const float*)d_in[2];
  const float* proj = (const float*)d_in[3];
  float* out = (float*)d_out;
  char* ws = (char*)d_ws;

  const size_t QP_OFF   = 0;             // bf16 [rows][266]  final qp
  const size_t KD_OFF   = 69730304ull;   // bf16 [rows][266]  s'_k (pre-exp)
  const size_t CTX_OFF  = 139460608ull;  // bf16 [1024][266][64] = 34,865,152
  const size_t Z_OFF    = 174325760ull;  // f32  [1024][266] = 1,089,536
  const size_t GMAX_OFF = 175415296ull;  // uint [1] (monotonic-encoded float max)
  if (ws_size < 175416000ull) return;

  ushort_t* qp   = (ushort_t*)(ws + QP_OFF);
  ushort_t* kd   = (ushort_t*)(ws + KD_OFF);
  ushort_t* ctx  = (ushort_t*)(ws + CTX_OFF);
  float* z       = (float*)(ws + Z_OFF);
  uint_t* gmaxu  = (uint_t*)(ws + GMAX_OFF);

  hipMemsetAsync(gmaxu, 0, 4, stream);   // encoded floor for atomicMax
  k_dash_both<<<2*(NROWS/128), 256, 0, stream>>>(q, k, proj, qp, kd, gmaxu);
  k_chunksum8<<<NBH*NCH, 256, 0, stream>>>(kd, v, gmaxu, ctx, z);
  k_prefix3  <<<NBH*67 + NBH, 256, 0, stream>>>(ctx, z);
  k_output11 <<<NBH*NCH, 512, 0, stream>>>(qp, kd, v, ctx, z, gmaxu, out);
}